// Round 6
// baseline (3671.820 us; speedup 1.0000x reference)
//
#include <hip/hip_runtime.h>
#include <cstddef>

#define NN 50000
#define EE 1600000
#define IN_DIM 512
#define HID 256
#define OUT_DIM 40
#define KSTEPS 10
#define BN_EPS 1e-5f

#define HB 256                 // histogram/scatter blocks
#define ECHUNK (EE / HB)       // 6250 edges per block
#define BNODE 40               // dest nodes per bucket
#define NB 1280                // buckets (covers 51200 >= NN)
#define HRW ((NN + 3) / 4)     // 12500 words of packed byte counts

typedef __attribute__((ext_vector_type(8))) short short8;
typedef __attribute__((ext_vector_type(4))) float f32x4;

__device__ inline unsigned short bf16_rne(float v) {
    union { float f; unsigned u; } c; c.f = v;
    unsigned u = c.u;
    unsigned r = u + 0x7fff + ((u >> 16) & 1);
    return (unsigned short)(r >> 16);
}
__device__ inline float bf16_to_f(unsigned short h) {
    union { unsigned u; float f; } c; c.u = ((unsigned)h) << 16;
    return c.f;
}

// ---------------- phase 1: LDS histograms (row-degree bytes + col buckets) ----------------
__global__ __launch_bounds__(256) void k_hist(const int* __restrict__ ei,
                                              unsigned* __restrict__ histR8,
                                              int* __restrict__ histB) {
    __shared__ unsigned hr[HRW];   // 50 KB: byte-packed per-node row counts
    __shared__ int hb[NB];         // 5 KB: bucket counts
    int b = blockIdx.x, tid = threadIdx.x;
    for (int i = tid; i < HRW; i += 256) hr[i] = 0;
    for (int i = tid; i < NB; i += 256) hb[i] = 0;
    __syncthreads();
    int e0 = b * ECHUNK;
    for (int e = e0 + tid; e < e0 + ECHUNK; e += 256) {
        int r = ei[e];
        int c = ei[EE + e];
        atomicAdd(&hr[r >> 2], 1u << ((r & 3) * 8));  // max ~5 per node per chunk << 255
        atomicAdd(&hb[(unsigned)c / BNODE], 1);
    }
    __syncthreads();
    unsigned* o = histR8 + (size_t)b * HRW;
    for (int i = tid; i < HRW; i += 256) o[i] = hr[i];
    int* ob = histB + (size_t)b * NB;
    for (int i = tid; i < NB; i += 256) ob[i] = hb[i];
}

// ---------------- row-degree reduce -> dinv ----------------
__global__ void k_dinv2(const unsigned* __restrict__ histR8, float* __restrict__ dinv) {
    int i = blockIdx.x * blockDim.x + threadIdx.x;
    if (i >= NN) return;
    int word = i >> 2, sh = (i & 3) * 8;
    int d = 0;
    for (int blk = 0; blk < HB; ++blk)
        d += (histR8[(size_t)blk * HRW + word] >> sh) & 0xFFu;
    float fd = d < 1 ? 1.0f : (float)d;
    dinv[i] = 1.0f / sqrtf(fd);
}

// ---------------- per-bucket prefix across blocks; histB[blk][t] -> prefix; totB = sums ----------------
__global__ void k_colsumB(int* __restrict__ histB, int* __restrict__ totB) {
    int t = blockIdx.x * blockDim.x + threadIdx.x;
    if (t >= NB) return;
    int run = 0;
    for (int blk = 0; blk < HB; ++blk) {
        size_t idx = (size_t)blk * NB + t;
        int v = histB[idx];
        histB[idx] = run;
        run += v;
    }
    totB[t] = run;
}

// ---------------- exclusive scan of 1280 bucket totals -> bptr ----------------
__global__ __launch_bounds__(256) void k_scanT(const int* __restrict__ totB,
                                               int* __restrict__ bptr) {
    __shared__ int wsum[4];
    int tid = threadIdx.x;
    int loc[5], s = 0;
#pragma unroll
    for (int j = 0; j < 5; ++j) { loc[j] = totB[tid * 5 + j]; s += loc[j]; }
    int lane = tid & 63, w = tid >> 6, v = s;
    for (int d = 1; d < 64; d <<= 1) {
        int t = __shfl_up(v, d);
        if (lane >= d) v += t;
    }
    if (lane == 63) wsum[w] = v;
    __syncthreads();
    if (w == 0 && lane < 4) {
        int t = wsum[lane];
        for (int d = 1; d < 4; d <<= 1) {
            int u = __shfl_up(t, d);
            if (lane >= d) t += u;
        }
        wsum[lane] = t;
    }
    __syncthreads();
    int run = (w > 0 ? wsum[w - 1] : 0) + (v - s);
#pragma unroll
    for (int j = 0; j < 5; ++j) { bptr[tid * 5 + j] = run; run += loc[j]; }
    if (tid == 255) bptr[NB] = run;   // == EE
}

// ---------------- phase 2: scatter into buckets via LDS cursors ----------------
__global__ __launch_bounds__(256) void k_scatterB(const int* __restrict__ ei,
                                                  const float* __restrict__ dinv,
                                                  const int* __restrict__ bptr,
                                                  const int* __restrict__ histB,
                                                  int2* __restrict__ ep) {
    __shared__ int cur[NB];
    int b = blockIdx.x, tid = threadIdx.x;
    for (int i = tid; i < NB; i += 256) cur[i] = bptr[i] + histB[(size_t)b * NB + i];
    __syncthreads();
    int e0 = b * ECHUNK;
    for (int e = e0 + tid; e < e0 + ECHUNK; e += 256) {
        int r = ei[e];
        int c = ei[EE + e];
        int bk = (unsigned)c / BNODE;
        int pos = atomicAdd(&cur[bk], 1);
        int2 p;
        p.x = r | ((c - bk * BNODE) << 16);   // row:16b | col_local:6b
        p.y = __float_as_int(dinv[r] * dinv[c]);
        ep[pos] = p;
    }
}

// ---------------- W1 -> bf16 hi/lo split ----------------
__global__ void k_w1split(const float* __restrict__ W1, unsigned short* __restrict__ w1h,
                          unsigned short* __restrict__ w1l) {
    int i = blockIdx.x * blockDim.x + threadIdx.x;
    if (i >= HID * IN_DIM) return;
    float v = W1[i];
    unsigned short h = bf16_rne(v);
    unsigned short l = bf16_rne(v - bf16_to_f(h));
    w1h[i] = h;
    w1l[i] = l;
}

// ---------------- GEMM1 via split-bf16 MFMA: h = relu(BN(x @ W1^T + b1)) ----------------
#define BM 64
#define BK 64
__global__ __launch_bounds__(512) void k_gemm1m(const float* __restrict__ x,
                                                const unsigned short* __restrict__ w1h,
                                                const unsigned short* __restrict__ w1l,
                                                const float* __restrict__ b1,
                                                const float* __restrict__ bnw,
                                                const float* __restrict__ bnb,
                                                const float* __restrict__ bnm,
                                                const float* __restrict__ bnv,
                                                float* __restrict__ h) {
    __shared__ __align__(16) unsigned short Ah[BM * BK];
    __shared__ __align__(16) unsigned short Al[BM * BK];
    __shared__ __align__(16) unsigned short Bh[HID * BK];
    __shared__ __align__(16) unsigned short Bl[HID * BK];
    int tid = threadIdx.x;
    int lane = tid & 63;
    int wid = tid >> 6;
    int wm = wid >> 2;
    int wn = wid & 3;
    int brow = blockIdx.x * BM;

    int ra = tid >> 3, ca = (tid & 7) * 8;
    int rb = tid >> 1, cb = (tid & 1) * 32;

    bool rok = (brow + ra) < NN;
    const float* xa = x + (size_t)(brow + ra) * IN_DIM + ca;
    const unsigned short* bhp = w1h + (size_t)rb * IN_DIM + cb;
    const unsigned short* blp = w1l + (size_t)rb * IN_DIM + cb;

    int abyte = (ra * BK + ca) * 2; abyte ^= (ra & 7) << 4;
    int bbyte0 = (rb * BK + cb) * 2;
    int bsw = (rb & 7) << 4;

    f32x4 acc[2][4];
#pragma unroll
    for (int i = 0; i < 2; ++i)
#pragma unroll
        for (int j = 0; j < 4; ++j) acc[i][j] = (f32x4){0.f, 0.f, 0.f, 0.f};

    int frow_a = wm * 32 + (lane & 15);
    int frow_b = wn * 64 + (lane & 15);
    int fk = (lane >> 4) * 16;

    for (int kt = 0; kt < IN_DIM; kt += BK) {
        float4 v0 = make_float4(0.f, 0.f, 0.f, 0.f), v1 = v0;
        if (rok) {
            v0 = *(const float4*)(xa + kt);
            v1 = *(const float4*)(xa + kt + 4);
        }
        short8 gb_h[4], gb_l[4];
#pragma unroll
        for (int q = 0; q < 4; ++q) {
            gb_h[q] = *(const short8*)(bhp + kt + q * 8);
            gb_l[q] = *(const short8*)(blp + kt + q * 8);
        }
        __syncthreads();
        union { unsigned short u[8]; short8 v; } uh, ul;
        float vv[8] = {v0.x, v0.y, v0.z, v0.w, v1.x, v1.y, v1.z, v1.w};
#pragma unroll
        for (int j = 0; j < 8; ++j) {
            unsigned short hh = bf16_rne(vv[j]);
            uh.u[j] = hh;
            ul.u[j] = bf16_rne(vv[j] - bf16_to_f(hh));
        }
        *(short8*)((char*)Ah + abyte) = uh.v;
        *(short8*)((char*)Al + abyte) = ul.v;
#pragma unroll
        for (int q = 0; q < 4; ++q) {
            int bb = (bbyte0 + q * 16) ^ bsw;
            *(short8*)((char*)Bh + bb) = gb_h[q];
            *(short8*)((char*)Bl + bb) = gb_l[q];
        }
        __syncthreads();

#pragma unroll
        for (int kk = 0; kk < 2; ++kk) {
            short8 afh[2], afl[2];
#pragma unroll
            for (int mi = 0; mi < 2; ++mi) {
                int row = frow_a + mi * 16;
                int byte = (row * BK * 2 + kk * 64 + fk) ^ ((row & 7) << 4);
                afh[mi] = *(short8*)((char*)Ah + byte);
                afl[mi] = *(short8*)((char*)Al + byte);
            }
#pragma unroll
            for (int ni = 0; ni < 4; ++ni) {
                int row = frow_b + ni * 16;
                int byte = (row * BK * 2 + kk * 64 + fk) ^ ((row & 7) << 4);
                short8 bh = *(short8*)((char*)Bh + byte);
                short8 bl = *(short8*)((char*)Bl + byte);
#pragma unroll
                for (int mi = 0; mi < 2; ++mi) {
                    acc[mi][ni] = __builtin_amdgcn_mfma_f32_16x16x32_bf16(afh[mi], bh, acc[mi][ni], 0, 0, 0);
                    acc[mi][ni] = __builtin_amdgcn_mfma_f32_16x16x32_bf16(afl[mi], bh, acc[mi][ni], 0, 0, 0);
                    acc[mi][ni] = __builtin_amdgcn_mfma_f32_16x16x32_bf16(afh[mi], bl, acc[mi][ni], 0, 0, 0);
                }
            }
        }
    }

    int cbase = wn * 64 + (lane & 15);
    float scl[4], off[4];
#pragma unroll
    for (int ni = 0; ni < 4; ++ni) {
        int c = cbase + ni * 16;
        float s = bnw[c] * rsqrtf(bnv[c] + BN_EPS);
        scl[ni] = s;
        off[ni] = (b1[c] - bnm[c]) * s + bnb[c];
    }
#pragma unroll
    for (int mi = 0; mi < 2; ++mi) {
        int r0 = brow + wm * 32 + mi * 16 + ((lane >> 4) << 2);
#pragma unroll
        for (int ni = 0; ni < 4; ++ni) {
            int c = cbase + ni * 16;
#pragma unroll
            for (int j = 0; j < 4; ++j) {
                int r = r0 + j;
                if (r < NN) {
                    float v = acc[mi][ni][j] * scl[ni] + off[ni];
                    h[(size_t)r * HID + c] = v > 0.f ? v : 0.f;
                }
            }
        }
    }
}

// ---------------- GEMM2: z = h @ W2^T + b2; ping = z; out = gamma0 * z ----------------
__global__ __launch_bounds__(256) void k_gemm2(const float* __restrict__ h,
                                               const float* __restrict__ W2,
                                               const float* __restrict__ b2,
                                               const float* __restrict__ gamma,
                                               float* __restrict__ ping,
                                               float* __restrict__ out) {
    __shared__ float W2T[HID * OUT_DIM];
    int tid = threadIdx.x;
    for (int i = tid; i < HID * OUT_DIM; i += 256) {
        int o = i / HID;
        int k = i - o * HID;
        W2T[k * OUT_DIM + o] = W2[i];
    }
    __syncthreads();
    int n = blockIdx.x * 256 + tid;
    if (n >= NN) return;

    float4 acc[10];
#pragma unroll
    for (int o4 = 0; o4 < 10; ++o4) acc[o4] = *(const float4*)&b2[o4 * 4];

    const float4* hr = (const float4*)(h + (size_t)n * HID);
    const float4* wt = (const float4*)W2T;
    for (int j = 0; j < HID / 4; ++j) {
        float4 hv = hr[j];
#pragma unroll
        for (int c = 0; c < 4; ++c) {
            float hk = (c == 0) ? hv.x : (c == 1) ? hv.y : (c == 2) ? hv.z : hv.w;
            const float4* wr = wt + (size_t)(j * 4 + c) * 10;
#pragma unroll
            for (int o4 = 0; o4 < 10; ++o4) {
                float4 w = wr[o4];
                acc[o4].x += hk * w.x;
                acc[o4].y += hk * w.y;
                acc[o4].z += hk * w.z;
                acc[o4].w += hk * w.w;
            }
        }
    }
    float g0 = gamma[0];
    float4* pp = (float4*)(ping + (size_t)n * OUT_DIM);
    float4* op = (float4*)(out + (size_t)n * OUT_DIM);
#pragma unroll
    for (int o4 = 0; o4 < 10; ++o4) {
        pp[o4] = acc[o4];
        float4 g;
        g.x = g0 * acc[o4].x; g.y = g0 * acc[o4].y;
        g.z = g0 * acc[o4].z; g.w = g0 * acc[o4].w;
        op[o4] = g;
    }
}

// ---------------- propagation step: bucket-per-block, LDS accumulate ----------------
// Each wave loads 64 edges coalesced (lane-per-edge), then broadcasts each edge
// via wave-uniform readlane (SGPR, no LDS) -> 8 independent gathers in flight.
__global__ __launch_bounds__(256) void k_spmm2(const int* __restrict__ bptr,
                                               const int2* __restrict__ ep,
                                               const float* __restrict__ cur,
                                               float* __restrict__ nxt,
                                               float* __restrict__ out,
                                               const float* __restrict__ gamma, int k) {
    __shared__ float sacc[BNODE * OUT_DIM];   // 6.4 KB
    int b = blockIdx.x, tid = threadIdx.x;
    for (int i = tid; i < BNODE * OUT_DIM; i += 256) sacc[i] = 0.f;
    __syncthreads();
    int e0 = bptr[b], e1 = bptr[b + 1];
    int lane = tid & 63, wv = tid >> 6;

    // split bucket edges into 4 contiguous wave chunks
    int total = e1 - e0;
    int per = (total + 3) >> 2;
    int wbeg = e0 + wv * per;
    int wend = wbeg + per < e1 ? wbeg + per : e1;

    bool act = lane < OUT_DIM;
    for (int base = wbeg; base < wend; base += 64) {
        int n = wend - base; if (n > 64) n = 64;
        int2 p = make_int2(0, 0);
        if (lane < n) p = ep[base + lane];   // coalesced 512B per wave
        int j = 0;
        for (; j + 8 <= n; j += 8) {
#pragma unroll
            for (int u = 0; u < 8; ++u) {
                int px = __builtin_amdgcn_readlane(p.x, j + u);
                float nm = __int_as_float(__builtin_amdgcn_readlane(p.y, j + u));
                int r = px & 0xFFFF, c = px >> 16;
                if (act) {
                    float v = cur[(size_t)r * OUT_DIM + lane];
                    atomicAdd(&sacc[c * OUT_DIM + lane], nm * v);
                }
            }
        }
        for (; j < n; ++j) {
            int px = __builtin_amdgcn_readlane(p.x, j);
            float nm = __int_as_float(__builtin_amdgcn_readlane(p.y, j));
            int r = px & 0xFFFF, c = px >> 16;
            if (act) {
                float v = cur[(size_t)r * OUT_DIM + lane];
                atomicAdd(&sacc[c * OUT_DIM + lane], nm * v);
            }
        }
    }
    __syncthreads();

    float gk = gamma[k];
    int base = b * BNODE;
    for (int i = tid; i < BNODE * OUT_DIM; i += 256) {
        int node = base + i / OUT_DIM;
        if (node < NN) {
            size_t o = (size_t)node * OUT_DIM + (i % OUT_DIM);
            float v = sacc[i];
            nxt[o] = v;
            out[o] += gk * v;
        }
    }
}

extern "C" void kernel_launch(void* const* d_in, const int* in_sizes, int n_in,
                              void* d_out, int out_size, void* d_ws, size_t ws_size,
                              hipStream_t stream) {
    const float* x   = (const float*)d_in[0];
    const int*   ei  = (const int*)d_in[1];
    const float* W1  = (const float*)d_in[2];
    const float* b1  = (const float*)d_in[3];
    const float* bnw = (const float*)d_in[4];
    const float* bnb = (const float*)d_in[5];
    const float* bnm = (const float*)d_in[6];
    const float* bnv = (const float*)d_in[7];
    const float* W2  = (const float*)d_in[8];
    const float* b2  = (const float*)d_in[9];
    const float* gamma = (const float*)d_in[10];
    float* out = (float*)d_out;

    char* ws = (char*)d_ws;
    const size_t A = 256;
    auto pad = [&](size_t b) { return (b + A - 1) / A * A; };
    size_t off = 0;
    int*   bptr   = (int*)  (ws + off); off += pad((size_t)(NB + 1) * 4);
    int*   totB   = (int*)  (ws + off); off += pad((size_t)NB * 4);
    float* dinv   = (float*)(ws + off); off += pad((size_t)NN * 4);
    int2*  epackB = (int2*) (ws + off); off += pad((size_t)EE * 8);
    float* h      = (float*)(ws + off); off += pad((size_t)NN * HID * 4);
    float* ping   = (float*)(ws + off); off += pad((size_t)NN * OUT_DIM * 4);
    float* pong   = (float*)(ws + off); off += pad((size_t)NN * OUT_DIM * 4);
    unsigned short* w1h = (unsigned short*)(ws + off); off += pad((size_t)HID * IN_DIM * 2);
    unsigned short* w1l = (unsigned short*)(ws + off); off += pad((size_t)HID * IN_DIM * 2);

    // histR8/histB alias h (h written later by gemm1m, after scatterB consumed them)
    unsigned* histR8 = (unsigned*)h;                              // HB*HRW*4 = 12.8 MB
    int* histB = (int*)((char*)h + (size_t)HB * HRW * 4);         // HB*NB*4 = 1.31 MB

    // graph build: LDS histograms -> 2D prefix -> bucketed scatter (no global atomics)
    k_hist<<<HB, 256, 0, stream>>>(ei, histR8, histB);
    k_dinv2<<<(NN + 255) / 256, 256, 0, stream>>>(histR8, dinv);
    k_colsumB<<<(NB + 255) / 256, 256, 0, stream>>>(histB, totB);
    k_scanT<<<1, 256, 0, stream>>>(totB, bptr);
    k_scatterB<<<HB, 256, 0, stream>>>(ei, dinv, bptr, histB, epackB);

    // MLP
    k_w1split<<<(HID * IN_DIM + 255) / 256, 256, 0, stream>>>(W1, w1h, w1l);
    k_gemm1m<<<(NN + BM - 1) / BM, 512, 0, stream>>>(x, w1h, w1l, b1, bnw, bnb, bnm, bnv, h);
    k_gemm2<<<(NN + 255) / 256, 256, 0, stream>>>(h, W2, b2, gamma, ping, out);

    // K propagation steps, ping-pong
    float* cur = ping;
    float* nxt = pong;
    for (int k = 1; k <= KSTEPS; ++k) {
        k_spmm2<<<NB, 256, 0, stream>>>(bptr, epackB, cur, nxt, out, gamma, k);
        float* t = cur; cur = nxt; nxt = t;
    }
}

// Round 7
// 731.216 us; speedup vs baseline: 5.0215x; 5.0215x over previous
//
#include <hip/hip_runtime.h>
#include <cstddef>

#define NN 50000
#define EE 1600000
#define IN_DIM 512
#define HID 256
#define OUT_DIM 40
#define KSTEPS 10
#define BN_EPS 1e-5f

#define HB 256                 // histogram/scatter blocks
#define ECHUNK (EE / HB)       // 6250 edges per block
#define BNODE 40               // dest nodes per bucket
#define NB 1280                // buckets (covers 51200 >= NN)
#define HRW ((NN + 3) / 4)     // 12500 words of packed byte counts
#define SORTCAP 3072           // max edges per bucket (mean 1250, sd ~35)

typedef __attribute__((ext_vector_type(8))) short short8;
typedef __attribute__((ext_vector_type(4))) float f32x4;

__device__ inline unsigned short bf16_rne(float v) {
    union { float f; unsigned u; } c; c.f = v;
    unsigned u = c.u;
    unsigned r = u + 0x7fff + ((u >> 16) & 1);
    return (unsigned short)(r >> 16);
}
__device__ inline float bf16_to_f(unsigned short h) {
    union { unsigned u; float f; } c; c.u = ((unsigned)h) << 16;
    return c.f;
}

// ---------------- phase 1: LDS histograms (row-degree bytes + col buckets) ----------------
__global__ __launch_bounds__(256) void k_hist(const int* __restrict__ ei,
                                              unsigned* __restrict__ histR8,
                                              int* __restrict__ histB) {
    __shared__ unsigned hr[HRW];   // 50 KB: byte-packed per-node row counts
    __shared__ int hb[NB];         // 5 KB: bucket counts
    int b = blockIdx.x, tid = threadIdx.x;
    for (int i = tid; i < HRW; i += 256) hr[i] = 0;
    for (int i = tid; i < NB; i += 256) hb[i] = 0;
    __syncthreads();
    int e0 = b * ECHUNK;
    for (int e = e0 + tid; e < e0 + ECHUNK; e += 256) {
        int r = ei[e];
        int c = ei[EE + e];
        atomicAdd(&hr[r >> 2], 1u << ((r & 3) * 8));  // max ~5 per node per chunk << 255
        atomicAdd(&hb[(unsigned)c / BNODE], 1);
    }
    __syncthreads();
    unsigned* o = histR8 + (size_t)b * HRW;
    for (int i = tid; i < HRW; i += 256) o[i] = hr[i];
    int* ob = histB + (size_t)b * NB;
    for (int i = tid; i < NB; i += 256) ob[i] = hb[i];
}

// ---------------- row-degree reduce -> dinv ----------------
__global__ void k_dinv2(const unsigned* __restrict__ histR8, float* __restrict__ dinv) {
    int i = blockIdx.x * blockDim.x + threadIdx.x;
    if (i >= NN) return;
    int word = i >> 2, sh = (i & 3) * 8;
    int d = 0;
    for (int blk = 0; blk < HB; ++blk)
        d += (histR8[(size_t)blk * HRW + word] >> sh) & 0xFFu;
    float fd = d < 1 ? 1.0f : (float)d;
    dinv[i] = 1.0f / sqrtf(fd);
}

// ---------------- per-bucket prefix across blocks ----------------
__global__ void k_colsumB(int* __restrict__ histB, int* __restrict__ totB) {
    int t = blockIdx.x * blockDim.x + threadIdx.x;
    if (t >= NB) return;
    int run = 0;
    for (int blk = 0; blk < HB; ++blk) {
        size_t idx = (size_t)blk * NB + t;
        int v = histB[idx];
        histB[idx] = run;
        run += v;
    }
    totB[t] = run;
}

// ---------------- exclusive scan of 1280 bucket totals -> bptr ----------------
__global__ __launch_bounds__(256) void k_scanT(const int* __restrict__ totB,
                                               int* __restrict__ bptr) {
    __shared__ int wsum[4];
    int tid = threadIdx.x;
    int loc[5], s = 0;
#pragma unroll
    for (int j = 0; j < 5; ++j) { loc[j] = totB[tid * 5 + j]; s += loc[j]; }
    int lane = tid & 63, w = tid >> 6, v = s;
    for (int d = 1; d < 64; d <<= 1) {
        int t = __shfl_up(v, d);
        if (lane >= d) v += t;
    }
    if (lane == 63) wsum[w] = v;
    __syncthreads();
    if (w == 0 && lane < 4) {
        int t = wsum[lane];
        for (int d = 1; d < 4; d <<= 1) {
            int u = __shfl_up(t, d);
            if (lane >= d) t += u;
        }
        wsum[lane] = t;
    }
    __syncthreads();
    int run = (w > 0 ? wsum[w - 1] : 0) + (v - s);
#pragma unroll
    for (int j = 0; j < 5; ++j) { bptr[tid * 5 + j] = run; run += loc[j]; }
    if (tid == 255) bptr[NB] = run;   // == EE
}

// ---------------- phase 2: scatter into buckets via LDS cursors ----------------
__global__ __launch_bounds__(256) void k_scatterB(const int* __restrict__ ei,
                                                  const float* __restrict__ dinv,
                                                  const int* __restrict__ bptr,
                                                  const int* __restrict__ histB,
                                                  int2* __restrict__ ep) {
    __shared__ int cur[NB];
    int b = blockIdx.x, tid = threadIdx.x;
    for (int i = tid; i < NB; i += 256) cur[i] = bptr[i] + histB[(size_t)b * NB + i];
    __syncthreads();
    int e0 = b * ECHUNK;
    for (int e = e0 + tid; e < e0 + ECHUNK; e += 256) {
        int r = ei[e];
        int c = ei[EE + e];
        int bk = (unsigned)c / BNODE;
        int pos = atomicAdd(&cur[bk], 1);
        int2 p;
        p.x = r | ((c - bk * BNODE) << 16);   // src:16b | col_local:6b
        p.y = __float_as_int(dinv[r] * dinv[c]);
        ep[pos] = p;
    }
}

// ---------------- phase 3: in-bucket sort to exact CSC + node ptr emit ----------------
__global__ __launch_bounds__(256) void k_sortB(const int* __restrict__ bptr,
                                               int2* __restrict__ ep,
                                               int* __restrict__ ptr) {
    __shared__ int2 buf[SORTCAP];   // 24 KB
    __shared__ int h40[BNODE];
    __shared__ int pfx[BNODE + 1];
    int b = blockIdx.x, tid = threadIdx.x;
    int e0 = bptr[b], e1 = bptr[b + 1], n = e1 - e0;
    if (tid < BNODE) h40[tid] = 0;
    __syncthreads();
    for (int i = tid; i < n; i += 256) {
        int2 p = ep[e0 + i];
        buf[i] = p;
        atomicAdd(&h40[p.x >> 16], 1);
    }
    __syncthreads();
    if (tid == 0) {
        int run = 0;
#pragma unroll
        for (int j = 0; j < BNODE; ++j) { pfx[j] = run; run += h40[j]; }
        pfx[BNODE] = run;
    }
    __syncthreads();
    if (tid < BNODE) {
        int node = b * BNODE + tid;
        if (node < NN) ptr[node] = e0 + pfx[tid];
        h40[tid] = pfx[tid];     // becomes cursor
    }
    if (tid == 64 && b * BNODE + BNODE >= NN) ptr[NN] = e1;  // last real bucket(s): EE
    __syncthreads();
    for (int i = tid; i < n; i += 256) {
        int2 p = buf[i];
        int cl = p.x >> 16;
        int pos = atomicAdd(&h40[cl], 1);
        int2 q;
        q.x = p.x & 0xFFFF;      // plain src index
        q.y = p.y;
        ep[e0 + pos] = q;
    }
}

// ---------------- W1 -> bf16 hi/lo split ----------------
__global__ void k_w1split(const float* __restrict__ W1, unsigned short* __restrict__ w1h,
                          unsigned short* __restrict__ w1l) {
    int i = blockIdx.x * blockDim.x + threadIdx.x;
    if (i >= HID * IN_DIM) return;
    float v = W1[i];
    unsigned short h = bf16_rne(v);
    unsigned short l = bf16_rne(v - bf16_to_f(h));
    w1h[i] = h;
    w1l[i] = l;
}

// ---------------- GEMM1 via split-bf16 MFMA: h = relu(BN(x @ W1^T + b1)) ----------------
#define BM 64
#define BK 64
__global__ __launch_bounds__(512) void k_gemm1m(const float* __restrict__ x,
                                                const unsigned short* __restrict__ w1h,
                                                const unsigned short* __restrict__ w1l,
                                                const float* __restrict__ b1,
                                                const float* __restrict__ bnw,
                                                const float* __restrict__ bnb,
                                                const float* __restrict__ bnm,
                                                const float* __restrict__ bnv,
                                                float* __restrict__ h) {
    __shared__ __align__(16) unsigned short Ah[BM * BK];
    __shared__ __align__(16) unsigned short Al[BM * BK];
    __shared__ __align__(16) unsigned short Bh[HID * BK];
    __shared__ __align__(16) unsigned short Bl[HID * BK];
    int tid = threadIdx.x;
    int lane = tid & 63;
    int wid = tid >> 6;
    int wm = wid >> 2;
    int wn = wid & 3;
    int brow = blockIdx.x * BM;

    int ra = tid >> 3, ca = (tid & 7) * 8;
    int rb = tid >> 1, cb = (tid & 1) * 32;

    bool rok = (brow + ra) < NN;
    const float* xa = x + (size_t)(brow + ra) * IN_DIM + ca;
    const unsigned short* bhp = w1h + (size_t)rb * IN_DIM + cb;
    const unsigned short* blp = w1l + (size_t)rb * IN_DIM + cb;

    int abyte = (ra * BK + ca) * 2; abyte ^= (ra & 7) << 4;
    int bbyte0 = (rb * BK + cb) * 2;
    int bsw = (rb & 7) << 4;

    f32x4 acc[2][4];
#pragma unroll
    for (int i = 0; i < 2; ++i)
#pragma unroll
        for (int j = 0; j < 4; ++j) acc[i][j] = (f32x4){0.f, 0.f, 0.f, 0.f};

    int frow_a = wm * 32 + (lane & 15);
    int frow_b = wn * 64 + (lane & 15);
    int fk = (lane >> 4) * 16;

    for (int kt = 0; kt < IN_DIM; kt += BK) {
        float4 v0 = make_float4(0.f, 0.f, 0.f, 0.f), v1 = v0;
        if (rok) {
            v0 = *(const float4*)(xa + kt);
            v1 = *(const float4*)(xa + kt + 4);
        }
        short8 gb_h[4], gb_l[4];
#pragma unroll
        for (int q = 0; q < 4; ++q) {
            gb_h[q] = *(const short8*)(bhp + kt + q * 8);
            gb_l[q] = *(const short8*)(blp + kt + q * 8);
        }
        __syncthreads();
        union { unsigned short u[8]; short8 v; } uh, ul;
        float vv[8] = {v0.x, v0.y, v0.z, v0.w, v1.x, v1.y, v1.z, v1.w};
#pragma unroll
        for (int j = 0; j < 8; ++j) {
            unsigned short hh = bf16_rne(vv[j]);
            uh.u[j] = hh;
            ul.u[j] = bf16_rne(vv[j] - bf16_to_f(hh));
        }
        *(short8*)((char*)Ah + abyte) = uh.v;
        *(short8*)((char*)Al + abyte) = ul.v;
#pragma unroll
        for (int q = 0; q < 4; ++q) {
            int bb = (bbyte0 + q * 16) ^ bsw;
            *(short8*)((char*)Bh + bb) = gb_h[q];
            *(short8*)((char*)Bl + bb) = gb_l[q];
        }
        __syncthreads();

#pragma unroll
        for (int kk = 0; kk < 2; ++kk) {
            short8 afh[2], afl[2];
#pragma unroll
            for (int mi = 0; mi < 2; ++mi) {
                int row = frow_a + mi * 16;
                int byte = (row * BK * 2 + kk * 64 + fk) ^ ((row & 7) << 4);
                afh[mi] = *(short8*)((char*)Ah + byte);
                afl[mi] = *(short8*)((char*)Al + byte);
            }
#pragma unroll
            for (int ni = 0; ni < 4; ++ni) {
                int row = frow_b + ni * 16;
                int byte = (row * BK * 2 + kk * 64 + fk) ^ ((row & 7) << 4);
                short8 bh = *(short8*)((char*)Bh + byte);
                short8 bl = *(short8*)((char*)Bl + byte);
#pragma unroll
                for (int mi = 0; mi < 2; ++mi) {
                    acc[mi][ni] = __builtin_amdgcn_mfma_f32_16x16x32_bf16(afh[mi], bh, acc[mi][ni], 0, 0, 0);
                    acc[mi][ni] = __builtin_amdgcn_mfma_f32_16x16x32_bf16(afl[mi], bh, acc[mi][ni], 0, 0, 0);
                    acc[mi][ni] = __builtin_amdgcn_mfma_f32_16x16x32_bf16(afh[mi], bl, acc[mi][ni], 0, 0, 0);
                }
            }
        }
    }

    int cbase = wn * 64 + (lane & 15);
    float scl[4], off[4];
#pragma unroll
    for (int ni = 0; ni < 4; ++ni) {
        int c = cbase + ni * 16;
        float s = bnw[c] * rsqrtf(bnv[c] + BN_EPS);
        scl[ni] = s;
        off[ni] = (b1[c] - bnm[c]) * s + bnb[c];
    }
#pragma unroll
    for (int mi = 0; mi < 2; ++mi) {
        int r0 = brow + wm * 32 + mi * 16 + ((lane >> 4) << 2);
#pragma unroll
        for (int ni = 0; ni < 4; ++ni) {
            int c = cbase + ni * 16;
#pragma unroll
            for (int j = 0; j < 4; ++j) {
                int r = r0 + j;
                if (r < NN) {
                    float v = acc[mi][ni][j] * scl[ni] + off[ni];
                    h[(size_t)r * HID + c] = v > 0.f ? v : 0.f;
                }
            }
        }
    }
}

// ---------------- GEMM2: z = h @ W2^T + b2; ping = z; out = gamma0 * z ----------------
__global__ __launch_bounds__(256) void k_gemm2(const float* __restrict__ h,
                                               const float* __restrict__ W2,
                                               const float* __restrict__ b2,
                                               const float* __restrict__ gamma,
                                               float* __restrict__ ping,
                                               float* __restrict__ out) {
    __shared__ float W2T[HID * OUT_DIM];
    int tid = threadIdx.x;
    for (int i = tid; i < HID * OUT_DIM; i += 256) {
        int o = i / HID;
        int k = i - o * HID;
        W2T[k * OUT_DIM + o] = W2[i];
    }
    __syncthreads();
    int n = blockIdx.x * 256 + tid;
    if (n >= NN) return;

    float4 acc[10];
#pragma unroll
    for (int o4 = 0; o4 < 10; ++o4) acc[o4] = *(const float4*)&b2[o4 * 4];

    const float4* hr = (const float4*)(h + (size_t)n * HID);
    const float4* wt = (const float4*)W2T;
    for (int j = 0; j < HID / 4; ++j) {
        float4 hv = hr[j];
#pragma unroll
        for (int c = 0; c < 4; ++c) {
            float hk = (c == 0) ? hv.x : (c == 1) ? hv.y : (c == 2) ? hv.z : hv.w;
            const float4* wr = wt + (size_t)(j * 4 + c) * 10;
#pragma unroll
            for (int o4 = 0; o4 < 10; ++o4) {
                float4 w = wr[o4];
                acc[o4].x += hk * w.x;
                acc[o4].y += hk * w.y;
                acc[o4].z += hk * w.z;
                acc[o4].w += hk * w.w;
            }
        }
    }
    float g0 = gamma[0];
    float4* pp = (float4*)(ping + (size_t)n * OUT_DIM);
    float4* op = (float4*)(out + (size_t)n * OUT_DIM);
#pragma unroll
    for (int o4 = 0; o4 < 10; ++o4) {
        pp[o4] = acc[o4];
        float4 g;
        g.x = g0 * acc[o4].x; g.y = g0 * acc[o4].y;
        g.z = g0 * acc[o4].z; g.w = g0 * acc[o4].w;
        op[o4] = g;
    }
}

// ---------------- propagation step: wave-per-node, lane-per-feature, 8-deep MLP ----------------
__global__ __launch_bounds__(256) void k_spmm3(const int* __restrict__ ptr,
                                               const int2* __restrict__ ep,
                                               const float* __restrict__ cur,
                                               float* __restrict__ nxt,
                                               float* __restrict__ out,
                                               const float* __restrict__ gamma, int k) {
    int wave = (blockIdx.x * blockDim.x + threadIdx.x) >> 6;
    int lane = threadIdx.x & 63;
    if (wave >= NN) return;
    int e0 = ptr[wave];
    int e1 = ptr[wave + 1];
    if (lane < OUT_DIM) {
        float a0 = 0.f, a1 = 0.f, a2 = 0.f, a3 = 0.f;
        float a4 = 0.f, a5 = 0.f, a6 = 0.f, a7 = 0.f;
        int e = e0;
        for (; e + 7 < e1; e += 8) {
            int2 p0 = ep[e],     p1 = ep[e + 1], p2 = ep[e + 2], p3 = ep[e + 3];
            int2 p4 = ep[e + 4], p5 = ep[e + 5], p6 = ep[e + 6], p7 = ep[e + 7];
            a0 += __int_as_float(p0.y) * cur[(size_t)p0.x * OUT_DIM + lane];
            a1 += __int_as_float(p1.y) * cur[(size_t)p1.x * OUT_DIM + lane];
            a2 += __int_as_float(p2.y) * cur[(size_t)p2.x * OUT_DIM + lane];
            a3 += __int_as_float(p3.y) * cur[(size_t)p3.x * OUT_DIM + lane];
            a4 += __int_as_float(p4.y) * cur[(size_t)p4.x * OUT_DIM + lane];
            a5 += __int_as_float(p5.y) * cur[(size_t)p5.x * OUT_DIM + lane];
            a6 += __int_as_float(p6.y) * cur[(size_t)p6.x * OUT_DIM + lane];
            a7 += __int_as_float(p7.y) * cur[(size_t)p7.x * OUT_DIM + lane];
        }
        for (; e < e1; ++e) {
            int2 p = ep[e];
            a0 += __int_as_float(p.y) * cur[(size_t)p.x * OUT_DIM + lane];
        }
        float acc = ((a0 + a1) + (a2 + a3)) + ((a4 + a5) + (a6 + a7));
        nxt[(size_t)wave * OUT_DIM + lane] = acc;
        out[(size_t)wave * OUT_DIM + lane] += gamma[k] * acc;
    }
}

extern "C" void kernel_launch(void* const* d_in, const int* in_sizes, int n_in,
                              void* d_out, int out_size, void* d_ws, size_t ws_size,
                              hipStream_t stream) {
    const float* x   = (const float*)d_in[0];
    const int*   ei  = (const int*)d_in[1];
    const float* W1  = (const float*)d_in[2];
    const float* b1  = (const float*)d_in[3];
    const float* bnw = (const float*)d_in[4];
    const float* bnb = (const float*)d_in[5];
    const float* bnm = (const float*)d_in[6];
    const float* bnv = (const float*)d_in[7];
    const float* W2  = (const float*)d_in[8];
    const float* b2  = (const float*)d_in[9];
    const float* gamma = (const float*)d_in[10];
    float* out = (float*)d_out;

    char* ws = (char*)d_ws;
    const size_t A = 256;
    auto pad = [&](size_t b) { return (b + A - 1) / A * A; };
    size_t off = 0;
    int*   bptr   = (int*)  (ws + off); off += pad((size_t)(NB + 1) * 4);
    int*   totB   = (int*)  (ws + off); off += pad((size_t)NB * 4);
    float* dinv   = (float*)(ws + off); off += pad((size_t)NN * 4);
    int*   ptr    = (int*)  (ws + off); off += pad((size_t)(NN + 1) * 4);
    int2*  epackB = (int2*) (ws + off); off += pad((size_t)EE * 8);
    float* h      = (float*)(ws + off); off += pad((size_t)NN * HID * 4);
    float* ping   = (float*)(ws + off); off += pad((size_t)NN * OUT_DIM * 4);
    float* pong   = (float*)(ws + off); off += pad((size_t)NN * OUT_DIM * 4);
    unsigned short* w1h = (unsigned short*)(ws + off); off += pad((size_t)HID * IN_DIM * 2);
    unsigned short* w1l = (unsigned short*)(ws + off); off += pad((size_t)HID * IN_DIM * 2);

    // histR8/histB alias h (h written later by gemm1m, after scatterB/sortB consumed them)
    unsigned* histR8 = (unsigned*)h;                              // HB*HRW*4 = 12.8 MB
    int* histB = (int*)((char*)h + (size_t)HB * HRW * 4);         // HB*NB*4 = 1.31 MB

    // graph build: LDS histograms -> 2D prefix -> bucketed scatter -> in-bucket CSC sort
    k_hist<<<HB, 256, 0, stream>>>(ei, histR8, histB);
    k_dinv2<<<(NN + 255) / 256, 256, 0, stream>>>(histR8, dinv);
    k_colsumB<<<(NB + 255) / 256, 256, 0, stream>>>(histB, totB);
    k_scanT<<<1, 256, 0, stream>>>(totB, bptr);
    k_scatterB<<<HB, 256, 0, stream>>>(ei, dinv, bptr, histB, epackB);
    k_sortB<<<NB, 256, 0, stream>>>(bptr, epackB, ptr);

    // MLP
    k_w1split<<<(HID * IN_DIM + 255) / 256, 256, 0, stream>>>(W1, w1h, w1l);
    k_gemm1m<<<(NN + BM - 1) / BM, 512, 0, stream>>>(x, w1h, w1l, b1, bnw, bnb, bnm, bnv, h);
    k_gemm2<<<(NN + 255) / 256, 256, 0, stream>>>(h, W2, b2, gamma, ping, out);

    // K propagation steps, ping-pong
    float* cur = ping;
    float* nxt = pong;
    for (int k = 1; k <= KSTEPS; ++k) {
        k_spmm3<<<(NN * 64 + 255) / 256, 256, 0, stream>>>(ptr, epackB, cur, nxt, out, gamma, k);
        float* t = cur; cur = nxt; nxt = t;
    }
}

// Round 8
// 715.118 us; speedup vs baseline: 5.1346x; 1.0225x over previous
//
#include <hip/hip_runtime.h>
#include <cstddef>

#define NN 50000
#define EE 1600000
#define IN_DIM 512
#define HID 256
#define OUT_DIM 40
#define KSTEPS 10
#define BN_EPS 1e-5f

#define HB 256                 // histogram/scatter blocks
#define ECHUNK (EE / HB)       // 6250 edges per block
#define BNODE 40               // dest nodes per bucket
#define NB 1280                // buckets (covers 51200 >= NN)
#define HRW ((NN + 3) / 4)     // 12500 words of packed byte counts
#define SORTCAP 3072           // max edges per bucket (mean 1250, sd ~35)

typedef __attribute__((ext_vector_type(8))) short short8;
typedef __attribute__((ext_vector_type(4))) float f32x4;

__device__ inline unsigned short bf16_rne(float v) {
    union { float f; unsigned u; } c; c.f = v;
    unsigned u = c.u;
    unsigned r = u + 0x7fff + ((u >> 16) & 1);
    return (unsigned short)(r >> 16);
}
__device__ inline float bf16_to_f(unsigned short h) {
    union { unsigned u; float f; } c; c.u = ((unsigned)h) << 16;
    return c.f;
}

// ---------------- phase 1: LDS histograms (row-degree bytes + col buckets) ----------------
__global__ __launch_bounds__(256) void k_hist(const int* __restrict__ ei,
                                              unsigned* __restrict__ histR8,
                                              int* __restrict__ histB) {
    __shared__ unsigned hr[HRW];   // 50 KB: byte-packed per-node row counts
    __shared__ int hb[NB];         // 5 KB: bucket counts
    int b = blockIdx.x, tid = threadIdx.x;
    for (int i = tid; i < HRW; i += 256) hr[i] = 0;
    for (int i = tid; i < NB; i += 256) hb[i] = 0;
    __syncthreads();
    int e0 = b * ECHUNK;
    for (int e = e0 + tid; e < e0 + ECHUNK; e += 256) {
        int r = ei[e];
        int c = ei[EE + e];
        atomicAdd(&hr[r >> 2], 1u << ((r & 3) * 8));  // max ~5 per node per chunk << 255
        atomicAdd(&hb[(unsigned)c / BNODE], 1);
    }
    __syncthreads();
    unsigned* o = histR8 + (size_t)b * HRW;
    for (int i = tid; i < HRW; i += 256) o[i] = hr[i];
    int* ob = histB + (size_t)b * NB;
    for (int i = tid; i < NB; i += 256) ob[i] = hb[i];
}

// ---------------- row-degree reduce -> dinv ----------------
__global__ void k_dinv2(const unsigned* __restrict__ histR8, float* __restrict__ dinv) {
    int i = blockIdx.x * blockDim.x + threadIdx.x;
    if (i >= NN) return;
    int word = i >> 2, sh = (i & 3) * 8;
    int d = 0;
    for (int blk = 0; blk < HB; ++blk)
        d += (histR8[(size_t)blk * HRW + word] >> sh) & 0xFFu;
    float fd = d < 1 ? 1.0f : (float)d;
    dinv[i] = 1.0f / sqrtf(fd);
}

// ---------------- per-bucket prefix across blocks ----------------
__global__ void k_colsumB(int* __restrict__ histB, int* __restrict__ totB) {
    int t = blockIdx.x * blockDim.x + threadIdx.x;
    if (t >= NB) return;
    int run = 0;
    for (int blk = 0; blk < HB; ++blk) {
        size_t idx = (size_t)blk * NB + t;
        int v = histB[idx];
        histB[idx] = run;
        run += v;
    }
    totB[t] = run;
}

// ---------------- exclusive scan of 1280 bucket totals -> bptr ----------------
__global__ __launch_bounds__(256) void k_scanT(const int* __restrict__ totB,
                                               int* __restrict__ bptr) {
    __shared__ int wsum[4];
    int tid = threadIdx.x;
    int loc[5], s = 0;
#pragma unroll
    for (int j = 0; j < 5; ++j) { loc[j] = totB[tid * 5 + j]; s += loc[j]; }
    int lane = tid & 63, w = tid >> 6, v = s;
    for (int d = 1; d < 64; d <<= 1) {
        int t = __shfl_up(v, d);
        if (lane >= d) v += t;
    }
    if (lane == 63) wsum[w] = v;
    __syncthreads();
    if (w == 0 && lane < 4) {
        int t = wsum[lane];
        for (int d = 1; d < 4; d <<= 1) {
            int u = __shfl_up(t, d);
            if (lane >= d) t += u;
        }
        wsum[lane] = t;
    }
    __syncthreads();
    int run = (w > 0 ? wsum[w - 1] : 0) + (v - s);
#pragma unroll
    for (int j = 0; j < 5; ++j) { bptr[tid * 5 + j] = run; run += loc[j]; }
    if (tid == 255) bptr[NB] = run;   // == EE
}

// ---------------- phase 2: scatter into buckets via LDS cursors ----------------
__global__ __launch_bounds__(256) void k_scatterB(const int* __restrict__ ei,
                                                  const float* __restrict__ dinv,
                                                  const int* __restrict__ bptr,
                                                  const int* __restrict__ histB,
                                                  int2* __restrict__ ep) {
    __shared__ int cur[NB];
    int b = blockIdx.x, tid = threadIdx.x;
    for (int i = tid; i < NB; i += 256) cur[i] = bptr[i] + histB[(size_t)b * NB + i];
    __syncthreads();
    int e0 = b * ECHUNK;
    for (int e = e0 + tid; e < e0 + ECHUNK; e += 256) {
        int r = ei[e];
        int c = ei[EE + e];
        int bk = (unsigned)c / BNODE;
        int pos = atomicAdd(&cur[bk], 1);
        int2 p;
        p.x = r | ((c - bk * BNODE) << 16);   // src:16b | col_local:6b
        p.y = __float_as_int(dinv[r] * dinv[c]);
        ep[pos] = p;
    }
}

// ---------------- phase 3: in-bucket sort to exact CSC + node ptr emit ----------------
__global__ __launch_bounds__(256) void k_sortB(const int* __restrict__ bptr,
                                               int2* __restrict__ ep,
                                               int* __restrict__ ptr) {
    __shared__ int2 buf[SORTCAP];   // 24 KB
    __shared__ int h40[BNODE];
    __shared__ int pfx[BNODE + 1];
    int b = blockIdx.x, tid = threadIdx.x;
    int e0 = bptr[b], e1 = bptr[b + 1], n = e1 - e0;
    if (tid < BNODE) h40[tid] = 0;
    __syncthreads();
    for (int i = tid; i < n; i += 256) {
        int2 p = ep[e0 + i];
        buf[i] = p;
        atomicAdd(&h40[p.x >> 16], 1);
    }
    __syncthreads();
    if (tid == 0) {
        int run = 0;
#pragma unroll
        for (int j = 0; j < BNODE; ++j) { pfx[j] = run; run += h40[j]; }
        pfx[BNODE] = run;
    }
    __syncthreads();
    if (tid < BNODE) {
        int node = b * BNODE + tid;
        if (node < NN) ptr[node] = e0 + pfx[tid];
        h40[tid] = pfx[tid];     // becomes cursor
    }
    if (tid == 64 && b * BNODE + BNODE >= NN) ptr[NN] = e1;  // last real bucket(s): EE
    __syncthreads();
    for (int i = tid; i < n; i += 256) {
        int2 p = buf[i];
        int cl = p.x >> 16;
        int pos = atomicAdd(&h40[cl], 1);
        int2 q;
        q.x = p.x & 0xFFFF;      // plain src index
        q.y = p.y;
        ep[e0 + pos] = q;
    }
}

// ---------------- W1 -> bf16 hi/lo split ----------------
__global__ void k_w1split(const float* __restrict__ W1, unsigned short* __restrict__ w1h,
                          unsigned short* __restrict__ w1l) {
    int i = blockIdx.x * blockDim.x + threadIdx.x;
    if (i >= HID * IN_DIM) return;
    float v = W1[i];
    unsigned short h = bf16_rne(v);
    unsigned short l = bf16_rne(v - bf16_to_f(h));
    w1h[i] = h;
    w1l[i] = l;
}

// ---------------- GEMM1 via split-bf16 MFMA: h = relu(BN(x @ W1^T + b1)) ----------------
// BM=128, BN=256 (full HID), BK=32. 8 waves, wave tile 64x64 (acc 4x4).
// 48 KB LDS; register-prefetch of tile kt+1 issued before the MFMA block.
#define BM 128
#define BK 32
__global__ __launch_bounds__(512, 2) void k_gemm1m(const float* __restrict__ x,
                                                   const unsigned short* __restrict__ w1h,
                                                   const unsigned short* __restrict__ w1l,
                                                   const float* __restrict__ b1,
                                                   const float* __restrict__ bnw,
                                                   const float* __restrict__ bnb,
                                                   const float* __restrict__ bnm,
                                                   const float* __restrict__ bnv,
                                                   float* __restrict__ h) {
    __shared__ __align__(16) unsigned short Ah[BM * BK];   // [128][32] 8 KB
    __shared__ __align__(16) unsigned short Al[BM * BK];
    __shared__ __align__(16) unsigned short Bh[HID * BK];  // [256][32] 16 KB
    __shared__ __align__(16) unsigned short Bl[HID * BK];
    int tid = threadIdx.x;
    int lane = tid & 63;
    int wid = tid >> 6;
    int wm = wid >> 2;            // 0..1  -> 64-row half
    int wn = wid & 3;             // 0..3  -> 64-col quarter
    int brow = blockIdx.x * BM;

    // A staging: 128 rows x 32 cols fp32; thread -> 8 floats
    int ra = tid >> 2, ca = (tid & 3) * 8;
    // B staging: 256 rows x 32 cols bf16 (x2 matrices); thread -> 16 bf16 each
    int rb = tid >> 1, cb = (tid & 1) * 16;

    bool rok = (brow + ra) < NN;
    const float* xa = x + (size_t)(brow + ra) * IN_DIM + ca;
    const unsigned short* bhp = w1h + (size_t)rb * IN_DIM + cb;
    const unsigned short* blp = w1l + (size_t)rb * IN_DIM + cb;

    f32x4 acc[4][4];
#pragma unroll
    for (int i = 0; i < 4; ++i)
#pragma unroll
        for (int j = 0; j < 4; ++j) acc[i][j] = (f32x4){0.f, 0.f, 0.f, 0.f};

    int frA = wm * 64 + (lane & 15);   // + mi*16 -> A row
    int frB = wn * 64 + (lane & 15);   // + ni*16 -> B row
    int fko = (lane >> 4) * 16;        // byte offset of this lane's 8-bf16 K-slice

    // register prefetch state
    float4 v0, v1;
    short8 gbh0, gbh1, gbl0, gbl1;
    {
        v0 = make_float4(0.f, 0.f, 0.f, 0.f); v1 = v0;
        if (rok) { v0 = *(const float4*)(xa); v1 = *(const float4*)(xa + 4); }
        gbh0 = *(const short8*)(bhp);     gbh1 = *(const short8*)(bhp + 8);
        gbl0 = *(const short8*)(blp);     gbl1 = *(const short8*)(blp + 8);
    }

    for (int kt = 0; kt < IN_DIM; kt += BK) {
        __syncthreads();   // previous tile's readers done
        {
            union { unsigned short u[8]; short8 v; } uh, ul;
            float vv[8] = {v0.x, v0.y, v0.z, v0.w, v1.x, v1.y, v1.z, v1.w};
#pragma unroll
            for (int j = 0; j < 8; ++j) {
                unsigned short hh = bf16_rne(vv[j]);
                uh.u[j] = hh;
                ul.u[j] = bf16_rne(vv[j] - bf16_to_f(hh));
            }
            *(short8*)&Ah[ra * BK + ca] = uh.v;
            *(short8*)&Al[ra * BK + ca] = ul.v;
            *(short8*)&Bh[rb * BK + cb] = gbh0;
            *(short8*)&Bh[rb * BK + cb + 8] = gbh1;
            *(short8*)&Bl[rb * BK + cb] = gbl0;
            *(short8*)&Bl[rb * BK + cb + 8] = gbl1;
        }
        __syncthreads();   // tile ready

        if (kt + BK < IN_DIM) {   // issue next-tile loads; latency hides under MFMAs
            int kn = kt + BK;
            v0 = make_float4(0.f, 0.f, 0.f, 0.f); v1 = v0;
            if (rok) { v0 = *(const float4*)(xa + kn); v1 = *(const float4*)(xa + kn + 4); }
            gbh0 = *(const short8*)(bhp + kn);     gbh1 = *(const short8*)(bhp + kn + 8);
            gbl0 = *(const short8*)(blp + kn);     gbl1 = *(const short8*)(blp + kn + 8);
        }

        short8 afh[4], afl[4];
#pragma unroll
        for (int mi = 0; mi < 4; ++mi) {
            int byte = (frA + mi * 16) * (BK * 2) + fko;
            afh[mi] = *(short8*)((char*)Ah + byte);
            afl[mi] = *(short8*)((char*)Al + byte);
        }
#pragma unroll
        for (int ni = 0; ni < 4; ++ni) {
            int byte = (frB + ni * 16) * (BK * 2) + fko;
            short8 bh = *(short8*)((char*)Bh + byte);
            short8 bl = *(short8*)((char*)Bl + byte);
#pragma unroll
            for (int mi = 0; mi < 4; ++mi) {
                acc[mi][ni] = __builtin_amdgcn_mfma_f32_16x16x32_bf16(afh[mi], bh, acc[mi][ni], 0, 0, 0);
                acc[mi][ni] = __builtin_amdgcn_mfma_f32_16x16x32_bf16(afl[mi], bh, acc[mi][ni], 0, 0, 0);
                acc[mi][ni] = __builtin_amdgcn_mfma_f32_16x16x32_bf16(afh[mi], bl, acc[mi][ni], 0, 0, 0);
            }
        }
    }

    // epilogue: BN + ReLU; C/D layout col=lane&15, row=(lane>>4)*4+j
    int cbase = wn * 64 + (lane & 15);
    float scl[4], off[4];
#pragma unroll
    for (int ni = 0; ni < 4; ++ni) {
        int c = cbase + ni * 16;
        float s = bnw[c] * rsqrtf(bnv[c] + BN_EPS);
        scl[ni] = s;
        off[ni] = (b1[c] - bnm[c]) * s + bnb[c];
    }
#pragma unroll
    for (int mi = 0; mi < 4; ++mi) {
        int r0 = brow + wm * 64 + mi * 16 + ((lane >> 4) << 2);
#pragma unroll
        for (int ni = 0; ni < 4; ++ni) {
            int c = cbase + ni * 16;
#pragma unroll
            for (int j = 0; j < 4; ++j) {
                int r = r0 + j;
                if (r < NN) {
                    float v = acc[mi][ni][j] * scl[ni] + off[ni];
                    h[(size_t)r * HID + c] = v > 0.f ? v : 0.f;
                }
            }
        }
    }
}

// ---------------- GEMM2: z = h @ W2^T + b2; ping = bf16(z); out = gamma0 * z ----------------
__global__ __launch_bounds__(256) void k_gemm2(const float* __restrict__ h,
                                               const float* __restrict__ W2,
                                               const float* __restrict__ b2,
                                               const float* __restrict__ gamma,
                                               unsigned short* __restrict__ ping,
                                               float* __restrict__ out) {
    __shared__ float W2T[HID * OUT_DIM];
    int tid = threadIdx.x;
    for (int i = tid; i < HID * OUT_DIM; i += 256) {
        int o = i / HID;
        int k = i - o * HID;
        W2T[k * OUT_DIM + o] = W2[i];
    }
    __syncthreads();
    int n = blockIdx.x * 256 + tid;
    if (n >= NN) return;

    float4 acc[10];
#pragma unroll
    for (int o4 = 0; o4 < 10; ++o4) acc[o4] = *(const float4*)&b2[o4 * 4];

    const float4* hr = (const float4*)(h + (size_t)n * HID);
    const float4* wt = (const float4*)W2T;
    for (int j = 0; j < HID / 4; ++j) {
        float4 hv = hr[j];
#pragma unroll
        for (int c = 0; c < 4; ++c) {
            float hk = (c == 0) ? hv.x : (c == 1) ? hv.y : (c == 2) ? hv.z : hv.w;
            const float4* wr = wt + (size_t)(j * 4 + c) * 10;
#pragma unroll
            for (int o4 = 0; o4 < 10; ++o4) {
                float4 w = wr[o4];
                acc[o4].x += hk * w.x;
                acc[o4].y += hk * w.y;
                acc[o4].z += hk * w.z;
                acc[o4].w += hk * w.w;
            }
        }
    }
    float g0 = gamma[0];
    uint2* pp = (uint2*)(ping + (size_t)n * OUT_DIM);
    float4* op = (float4*)(out + (size_t)n * OUT_DIM);
#pragma unroll
    for (int o4 = 0; o4 < 10; ++o4) {
        uint2 w;
        w.x = (unsigned)bf16_rne(acc[o4].x) | ((unsigned)bf16_rne(acc[o4].y) << 16);
        w.y = (unsigned)bf16_rne(acc[o4].z) | ((unsigned)bf16_rne(acc[o4].w) << 16);
        pp[o4] = w;
        float4 g;
        g.x = g0 * acc[o4].x; g.y = g0 * acc[o4].y;
        g.z = g0 * acc[o4].z; g.w = g0 * acc[o4].w;
        op[o4] = g;
    }
}

// ---------------- propagation step: wave-per-node, lane-per-feature, bf16 state ----------------
__global__ __launch_bounds__(256) void k_spmm3(const int* __restrict__ ptr,
                                               const int2* __restrict__ ep,
                                               const unsigned short* __restrict__ cur,
                                               unsigned short* __restrict__ nxt,
                                               float* __restrict__ out,
                                               const float* __restrict__ gamma, int k) {
    int wave = (blockIdx.x * blockDim.x + threadIdx.x) >> 6;
    int lane = threadIdx.x & 63;
    if (wave >= NN) return;
    int e0 = ptr[wave];
    int e1 = ptr[wave + 1];
    if (lane < OUT_DIM) {
        float a0 = 0.f, a1 = 0.f, a2 = 0.f, a3 = 0.f;
        float a4 = 0.f, a5 = 0.f, a6 = 0.f, a7 = 0.f;
        int e = e0;
        for (; e + 7 < e1; e += 8) {
            int2 p0 = ep[e],     p1 = ep[e + 1], p2 = ep[e + 2], p3 = ep[e + 3];
            int2 p4 = ep[e + 4], p5 = ep[e + 5], p6 = ep[e + 6], p7 = ep[e + 7];
            a0 += __int_as_float(p0.y) * bf16_to_f(cur[p0.x * OUT_DIM + lane]);
            a1 += __int_as_float(p1.y) * bf16_to_f(cur[p1.x * OUT_DIM + lane]);
            a2 += __int_as_float(p2.y) * bf16_to_f(cur[p2.x * OUT_DIM + lane]);
            a3 += __int_as_float(p3.y) * bf16_to_f(cur[p3.x * OUT_DIM + lane]);
            a4 += __int_as_float(p4.y) * bf16_to_f(cur[p4.x * OUT_DIM + lane]);
            a5 += __int_as_float(p5.y) * bf16_to_f(cur[p5.x * OUT_DIM + lane]);
            a6 += __int_as_float(p6.y) * bf16_to_f(cur[p6.x * OUT_DIM + lane]);
            a7 += __int_as_float(p7.y) * bf16_to_f(cur[p7.x * OUT_DIM + lane]);
        }
        for (; e < e1; ++e) {
            int2 p = ep[e];
            a0 += __int_as_float(p.y) * bf16_to_f(cur[p.x * OUT_DIM + lane]);
        }
        float acc = ((a0 + a1) + (a2 + a3)) + ((a4 + a5) + (a6 + a7));
        nxt[wave * OUT_DIM + lane] = bf16_rne(acc);
        out[wave * OUT_DIM + lane] += gamma[k] * acc;
    }
}

extern "C" void kernel_launch(void* const* d_in, const int* in_sizes, int n_in,
                              void* d_out, int out_size, void* d_ws, size_t ws_size,
                              hipStream_t stream) {
    const float* x   = (const float*)d_in[0];
    const int*   ei  = (const int*)d_in[1];
    const float* W1  = (const float*)d_in[2];
    const float* b1  = (const float*)d_in[3];
    const float* bnw = (const float*)d_in[4];
    const float* bnb = (const float*)d_in[5];
    const float* bnm = (const float*)d_in[6];
    const float* bnv = (const float*)d_in[7];
    const float* W2  = (const float*)d_in[8];
    const float* b2  = (const float*)d_in[9];
    const float* gamma = (const float*)d_in[10];
    float* out = (float*)d_out;

    char* ws = (char*)d_ws;
    const size_t A = 256;
    auto pad = [&](size_t b) { return (b + A - 1) / A * A; };
    size_t off = 0;
    int*   bptr   = (int*)  (ws + off); off += pad((size_t)(NB + 1) * 4);
    int*   totB   = (int*)  (ws + off); off += pad((size_t)NB * 4);
    float* dinv   = (float*)(ws + off); off += pad((size_t)NN * 4);
    int*   ptr    = (int*)  (ws + off); off += pad((size_t)(NN + 1) * 4);
    int2*  epackB = (int2*) (ws + off); off += pad((size_t)EE * 8);
    float* h      = (float*)(ws + off); off += pad((size_t)NN * HID * 4);
    unsigned short* ping = (unsigned short*)(ws + off); off += pad((size_t)NN * OUT_DIM * 2);
    unsigned short* pong = (unsigned short*)(ws + off); off += pad((size_t)NN * OUT_DIM * 2);
    unsigned short* w1h = (unsigned short*)(ws + off); off += pad((size_t)HID * IN_DIM * 2);
    unsigned short* w1l = (unsigned short*)(ws + off); off += pad((size_t)HID * IN_DIM * 2);

    // histR8/histB alias h (h written later by gemm1m, after scatterB/sortB consumed them)
    unsigned* histR8 = (unsigned*)h;                              // HB*HRW*4 = 12.8 MB
    int* histB = (int*)((char*)h + (size_t)HB * HRW * 4);         // HB*NB*4 = 1.31 MB

    // graph build: LDS histograms -> 2D prefix -> bucketed scatter -> in-bucket CSC sort
    k_hist<<<HB, 256, 0, stream>>>(ei, histR8, histB);
    k_dinv2<<<(NN + 255) / 256, 256, 0, stream>>>(histR8, dinv);
    k_colsumB<<<(NB + 255) / 256, 256, 0, stream>>>(histB, totB);
    k_scanT<<<1, 256, 0, stream>>>(totB, bptr);
    k_scatterB<<<HB, 256, 0, stream>>>(ei, dinv, bptr, histB, epackB);
    k_sortB<<<NB, 256, 0, stream>>>(bptr, epackB, ptr);

    // MLP
    k_w1split<<<(HID * IN_DIM + 255) / 256, 256, 0, stream>>>(W1, w1h, w1l);
    k_gemm1m<<<(NN + BM - 1) / BM, 512, 0, stream>>>(x, w1h, w1l, b1, bnw, bnb, bnm, bnv, h);
    k_gemm2<<<(NN + 255) / 256, 256, 0, stream>>>(h, W2, b2, gamma, ping, out);

    // K propagation steps, ping-pong (bf16 state, fp32 out accumulation)
    unsigned short* cur = ping;
    unsigned short* nxt = pong;
    for (int k = 1; k <= KSTEPS; ++k) {
        k_spmm3<<<(NN * 64 + 255) / 256, 256, 0, stream>>>(ptr, epackB, cur, nxt, out, gamma, k);
        unsigned short* t = cur; cur = nxt; nxt = t;
    }
}

// Round 9
// 535.343 us; speedup vs baseline: 6.8588x; 1.3358x over previous
//
#include <hip/hip_runtime.h>
#include <cstddef>

#define NN 50000
#define EE 1600000
#define IN_DIM 512
#define HID 256
#define OUT_DIM 40
#define KSTEPS 10
#define BN_EPS 1e-5f

#define HB 256                 // histogram/scatter blocks
#define ECHUNK (EE / HB)       // 6250 edges per block
#define BNODE 40               // dest nodes per bucket
#define NB 1280                // buckets (covers 51200 >= NN)
#define HRW ((NN + 3) / 4)     // 12500 words of packed byte counts
#define SORTCAP 3072           // max edges per bucket (mean 1250)

typedef __attribute__((ext_vector_type(8))) short short8;
typedef __attribute__((ext_vector_type(4))) float f32x4;

__device__ inline unsigned short bf16_rne(float v) {
    union { float f; unsigned u; } c; c.f = v;
    unsigned u = c.u;
    unsigned r = u + 0x7fff + ((u >> 16) & 1);
    return (unsigned short)(r >> 16);
}
__device__ inline float bf16_to_f(unsigned short h) {
    union { unsigned u; float f; } c; c.u = ((unsigned)h) << 16;
    return c.f;
}

// ---------------- phase 1: LDS histograms (row-degree bytes + col buckets) ----------------
__global__ __launch_bounds__(256) void k_hist(const int* __restrict__ ei,
                                              unsigned* __restrict__ histR8,
                                              int* __restrict__ histB) {
    __shared__ unsigned hr[HRW];   // 50 KB
    __shared__ int hb[NB];         // 5 KB
    int b = blockIdx.x, tid = threadIdx.x;
    for (int i = tid; i < HRW; i += 256) hr[i] = 0;
    for (int i = tid; i < NB; i += 256) hb[i] = 0;
    __syncthreads();
    int e0 = b * ECHUNK;
    for (int e = e0 + tid; e < e0 + ECHUNK; e += 256) {
        int r = ei[e];
        int c = ei[EE + e];
        atomicAdd(&hr[r >> 2], 1u << ((r & 3) * 8));
        atomicAdd(&hb[(unsigned)c / BNODE], 1);
    }
    __syncthreads();
    unsigned* o = histR8 + (size_t)b * HRW;
    for (int i = tid; i < HRW; i += 256) o[i] = hr[i];
    int* ob = histB + (size_t)b * NB;
    for (int i = tid; i < NB; i += 256) ob[i] = hb[i];
}

// ---------------- row-degree reduce -> dinv ----------------
__global__ void k_dinv2(const unsigned* __restrict__ histR8, float* __restrict__ dinv) {
    int i = blockIdx.x * blockDim.x + threadIdx.x;
    if (i >= NN) return;
    int word = i >> 2, sh = (i & 3) * 8;
    int d = 0;
    for (int blk = 0; blk < HB; ++blk)
        d += (histR8[(size_t)blk * HRW + word] >> sh) & 0xFFu;
    float fd = d < 1 ? 1.0f : (float)d;
    dinv[i] = 1.0f / sqrtf(fd);
}

// ---------------- per-bucket prefix across blocks ----------------
__global__ void k_colsumB(int* __restrict__ histB, int* __restrict__ totB) {
    int t = blockIdx.x * blockDim.x + threadIdx.x;
    if (t >= NB) return;
    int run = 0;
    for (int blk = 0; blk < HB; ++blk) {
        size_t idx = (size_t)blk * NB + t;
        int v = histB[idx];
        histB[idx] = run;
        run += v;
    }
    totB[t] = run;
}

// ---------------- exclusive scan of 1280 bucket totals -> bptr ----------------
__global__ __launch_bounds__(256) void k_scanT(const int* __restrict__ totB,
                                               int* __restrict__ bptr) {
    __shared__ int wsum[4];
    int tid = threadIdx.x;
    int loc[5], s = 0;
#pragma unroll
    for (int j = 0; j < 5; ++j) { loc[j] = totB[tid * 5 + j]; s += loc[j]; }
    int lane = tid & 63, w = tid >> 6, v = s;
    for (int d = 1; d < 64; d <<= 1) {
        int t = __shfl_up(v, d);
        if (lane >= d) v += t;
    }
    if (lane == 63) wsum[w] = v;
    __syncthreads();
    if (w == 0 && lane < 4) {
        int t = wsum[lane];
        for (int d = 1; d < 4; d <<= 1) {
            int u = __shfl_up(t, d);
            if (lane >= d) t += u;
        }
        wsum[lane] = t;
    }
    __syncthreads();
    int run = (w > 0 ? wsum[w - 1] : 0) + (v - s);
#pragma unroll
    for (int j = 0; j < 5; ++j) { bptr[tid * 5 + j] = run; run += loc[j]; }
    if (tid == 255) bptr[NB] = run;   // == EE
}

// ---------------- phase 2: scatter into buckets via LDS cursors ----------------
__global__ __launch_bounds__(256) void k_scatterB(const int* __restrict__ ei,
                                                  const float* __restrict__ dinv,
                                                  const int* __restrict__ bptr,
                                                  const int* __restrict__ histB,
                                                  int2* __restrict__ ep) {
    __shared__ int cur[NB];
    int b = blockIdx.x, tid = threadIdx.x;
    for (int i = tid; i < NB; i += 256) cur[i] = bptr[i] + histB[(size_t)b * NB + i];
    __syncthreads();
    int e0 = b * ECHUNK;
    for (int e = e0 + tid; e < e0 + ECHUNK; e += 256) {
        int r = ei[e];
        int c = ei[EE + e];
        int bk = (unsigned)c / BNODE;
        int pos = atomicAdd(&cur[bk], 1);
        int2 p;
        p.x = r | ((c - bk * BNODE) << 16);   // src:16b | col_local:6b
        p.y = __float_as_int(dinv[r] * dinv[c]);
        ep[pos] = p;
    }
}

// ---------------- phase 3: in-bucket sort to exact CSC + node ptr emit ----------------
__global__ __launch_bounds__(256) void k_sortB(const int* __restrict__ bptr,
                                               int2* __restrict__ ep,
                                               int* __restrict__ ptr) {
    __shared__ int2 buf[SORTCAP];   // 24 KB
    __shared__ int h40[BNODE];
    __shared__ int pfx[BNODE + 1];
    int b = blockIdx.x, tid = threadIdx.x;
    int e0 = bptr[b], e1 = bptr[b + 1], n = e1 - e0;
    if (tid < BNODE) h40[tid] = 0;
    __syncthreads();
    for (int i = tid; i < n; i += 256) {
        int2 p = ep[e0 + i];
        buf[i] = p;
        atomicAdd(&h40[p.x >> 16], 1);
    }
    __syncthreads();
    if (tid == 0) {
        int run = 0;
#pragma unroll
        for (int j = 0; j < BNODE; ++j) { pfx[j] = run; run += h40[j]; }
        pfx[BNODE] = run;
    }
    __syncthreads();
    if (tid < BNODE) {
        int node = b * BNODE + tid;
        if (node < NN) ptr[node] = e0 + pfx[tid];
        h40[tid] = pfx[tid];     // becomes cursor
    }
    if (tid == 64 && b * BNODE + BNODE >= NN) ptr[NN] = e1;
    __syncthreads();
    for (int i = tid; i < n; i += 256) {
        int2 p = buf[i];
        int cl = p.x >> 16;
        int pos = atomicAdd(&h40[cl], 1);
        int2 q;
        q.x = p.x & 0xFFFF;      // plain src index
        q.y = p.y;
        ep[e0 + pos] = q;
    }
}

// ---------------- W1 -> bf16 hi/lo split ----------------
__global__ void k_w1split(const float* __restrict__ W1, unsigned short* __restrict__ w1h,
                          unsigned short* __restrict__ w1l) {
    int i = blockIdx.x * blockDim.x + threadIdx.x;
    if (i >= HID * IN_DIM) return;
    float v = W1[i];
    unsigned short h = bf16_rne(v);
    unsigned short l = bf16_rne(v - bf16_to_f(h));
    w1h[i] = h;
    w1l[i] = l;
}

// ---------------- GEMM1 via split-bf16 MFMA: h = relu(BN(x @ W1^T + b1)) ----------------
// BM=64, BN=256 (full HID), BK=32. 4 waves, wave tile 64x64 (acc 4x4).
// 40 KB LDS, 3 blocks/CU. XOR-swizzled LDS (64B rows): byte ^= ((row>>1)&3)<<4.
#define BM 64
#define BK 32
__device__ inline int swzA(int row, int b) {
    return row * 64 + (b ^ (int)((((unsigned)row >> 1) & 3u) << 4));
}
__global__ __launch_bounds__(256, 3) void k_gemm1m(const float* __restrict__ x,
                                                   const unsigned short* __restrict__ w1h,
                                                   const unsigned short* __restrict__ w1l,
                                                   const float* __restrict__ b1,
                                                   const float* __restrict__ bnw,
                                                   const float* __restrict__ bnb,
                                                   const float* __restrict__ bnm,
                                                   const float* __restrict__ bnv,
                                                   float* __restrict__ h) {
    __shared__ __align__(16) unsigned short Ah[BM * BK];   // 4 KB
    __shared__ __align__(16) unsigned short Al[BM * BK];
    __shared__ __align__(16) unsigned short Bh[HID * BK];  // 16 KB
    __shared__ __align__(16) unsigned short Bl[HID * BK];
    int tid = threadIdx.x;
    int lane = tid & 63;
    int wn = tid >> 6;            // 0..3 -> 64-col quarter
    int brow = blockIdx.x * BM;

    // staging: 4 threads per row, one 16B chunk each
    int ra = tid >> 2, ck = tid & 3;     // A rows 0..63 / B rows 0..63 (+p*64)

    bool rok = (brow + ra) < NN;
    const float* xa = x + (size_t)(brow + ra) * IN_DIM + ck * 8;
    const unsigned short* bhp = w1h + (size_t)ra * IN_DIM + ck * 8;
    const unsigned short* blp = w1l + (size_t)ra * IN_DIM + ck * 8;

    f32x4 acc[4][4];
#pragma unroll
    for (int i = 0; i < 4; ++i)
#pragma unroll
        for (int j = 0; j < 4; ++j) acc[i][j] = (f32x4){0.f, 0.f, 0.f, 0.f};

    int frA = lane & 15;               // + mi*16 -> A row (full BM)
    int frB = wn * 64 + (lane & 15);   // + ni*16 -> B row
    int fko = (lane >> 4) * 16;        // byte offset of lane's 8-bf16 K-slice

    // register prefetch state
    float4 v0, v1;
    short8 gbh[4], gbl[4];
    v0 = make_float4(0.f, 0.f, 0.f, 0.f); v1 = v0;
    if (rok) { v0 = *(const float4*)(xa); v1 = *(const float4*)(xa + 4); }
#pragma unroll
    for (int p = 0; p < 4; ++p) {
        gbh[p] = *(const short8*)(bhp + (size_t)p * 64 * IN_DIM);
        gbl[p] = *(const short8*)(blp + (size_t)p * 64 * IN_DIM);
    }

    for (int kt = 0; kt < IN_DIM; kt += BK) {
        __syncthreads();   // previous tile's readers done
        {
            union { unsigned short u[8]; short8 v; } uh, ul;
            float vv[8] = {v0.x, v0.y, v0.z, v0.w, v1.x, v1.y, v1.z, v1.w};
#pragma unroll
            for (int j = 0; j < 8; ++j) {
                unsigned short hh = bf16_rne(vv[j]);
                uh.u[j] = hh;
                ul.u[j] = bf16_rne(vv[j] - bf16_to_f(hh));
            }
            int ab = swzA(ra, ck * 16);
            *(short8*)((char*)Ah + ab) = uh.v;
            *(short8*)((char*)Al + ab) = ul.v;
#pragma unroll
            for (int p = 0; p < 4; ++p) {
                int bb = swzA(ra + p * 64, ck * 16);
                *(short8*)((char*)Bh + bb) = gbh[p];
                *(short8*)((char*)Bl + bb) = gbl[p];
            }
        }
        __syncthreads();   // tile ready

        if (kt + BK < IN_DIM) {   // issue next-tile loads under the MFMAs
            int kn = kt + BK;
            v0 = make_float4(0.f, 0.f, 0.f, 0.f); v1 = v0;
            if (rok) { v0 = *(const float4*)(xa + kn); v1 = *(const float4*)(xa + kn + 4); }
#pragma unroll
            for (int p = 0; p < 4; ++p) {
                gbh[p] = *(const short8*)(bhp + kn + (size_t)p * 64 * IN_DIM);
                gbl[p] = *(const short8*)(blp + kn + (size_t)p * 64 * IN_DIM);
            }
        }

        short8 afh[4], afl[4];
#pragma unroll
        for (int mi = 0; mi < 4; ++mi) {
            int byte = swzA(frA + mi * 16, fko);
            afh[mi] = *(short8*)((char*)Ah + byte);
            afl[mi] = *(short8*)((char*)Al + byte);
        }
#pragma unroll
        for (int ni = 0; ni < 4; ++ni) {
            int byte = swzA(frB + ni * 16, fko);
            short8 bh = *(short8*)((char*)Bh + byte);
            short8 bl = *(short8*)((char*)Bl + byte);
#pragma unroll
            for (int mi = 0; mi < 4; ++mi) {
                acc[mi][ni] = __builtin_amdgcn_mfma_f32_16x16x32_bf16(afh[mi], bh, acc[mi][ni], 0, 0, 0);
                acc[mi][ni] = __builtin_amdgcn_mfma_f32_16x16x32_bf16(afl[mi], bh, acc[mi][ni], 0, 0, 0);
                acc[mi][ni] = __builtin_amdgcn_mfma_f32_16x16x32_bf16(afh[mi], bl, acc[mi][ni], 0, 0, 0);
            }
        }
    }

    // epilogue: BN + ReLU; C/D layout col=lane&15, row=(lane>>4)*4+j
    int cbase = wn * 64 + (lane & 15);
    float scl[4], off[4];
#pragma unroll
    for (int ni = 0; ni < 4; ++ni) {
        int c = cbase + ni * 16;
        float s = bnw[c] * rsqrtf(bnv[c] + BN_EPS);
        scl[ni] = s;
        off[ni] = (b1[c] - bnm[c]) * s + bnb[c];
    }
#pragma unroll
    for (int mi = 0; mi < 4; ++mi) {
        int r0 = brow + mi * 16 + ((lane >> 4) << 2);
#pragma unroll
        for (int ni = 0; ni < 4; ++ni) {
            int c = cbase + ni * 16;
#pragma unroll
            for (int j = 0; j < 4; ++j) {
                int r = r0 + j;
                if (r < NN) {
                    float v = acc[mi][ni][j] * scl[ni] + off[ni];
                    h[(size_t)r * HID + c] = v > 0.f ? v : 0.f;
                }
            }
        }
    }
}

// ---------------- GEMM2: z = h @ W2^T + b2; ping = bf16(z); out = gamma0 * z ----------------
__global__ __launch_bounds__(256) void k_gemm2(const float* __restrict__ h,
                                               const float* __restrict__ W2,
                                               const float* __restrict__ b2,
                                               const float* __restrict__ gamma,
                                               unsigned short* __restrict__ ping,
                                               float* __restrict__ out) {
    __shared__ float W2T[HID * OUT_DIM];
    int tid = threadIdx.x;
    for (int i = tid; i < HID * OUT_DIM; i += 256) {
        int o = i / HID;
        int k = i - o * HID;
        W2T[k * OUT_DIM + o] = W2[i];
    }
    __syncthreads();
    int n = blockIdx.x * 256 + tid;
    if (n >= NN) return;

    float4 acc[10];
#pragma unroll
    for (int o4 = 0; o4 < 10; ++o4) acc[o4] = *(const float4*)&b2[o4 * 4];

    const float4* hr = (const float4*)(h + (size_t)n * HID);
    const float4* wt = (const float4*)W2T;
    for (int j = 0; j < HID / 4; ++j) {
        float4 hv = hr[j];
#pragma unroll
        for (int c = 0; c < 4; ++c) {
            float hk = (c == 0) ? hv.x : (c == 1) ? hv.y : (c == 2) ? hv.z : hv.w;
            const float4* wr = wt + (size_t)(j * 4 + c) * 10;
#pragma unroll
            for (int o4 = 0; o4 < 10; ++o4) {
                float4 w = wr[o4];
                acc[o4].x += hk * w.x;
                acc[o4].y += hk * w.y;
                acc[o4].z += hk * w.z;
                acc[o4].w += hk * w.w;
            }
        }
    }
    float g0 = gamma[0];
    uint2* pp = (uint2*)(ping + (size_t)n * OUT_DIM);
    float4* op = (float4*)(out + (size_t)n * OUT_DIM);
#pragma unroll
    for (int o4 = 0; o4 < 10; ++o4) {
        uint2 w;
        w.x = (unsigned)bf16_rne(acc[o4].x) | ((unsigned)bf16_rne(acc[o4].y) << 16);
        w.y = (unsigned)bf16_rne(acc[o4].z) | ((unsigned)bf16_rne(acc[o4].w) << 16);
        pp[o4] = w;
        float4 g;
        g.x = g0 * acc[o4].x; g.y = g0 * acc[o4].y;
        g.z = g0 * acc[o4].z; g.w = g0 * acc[o4].w;
        op[o4] = g;
    }
}

// ---------------- propagation step: wave-per-node, 12 edges/round, dwordx2 gathers ----------------
// lane -> (edge_slot es=lane/10, feature_quad fq=lane%10); 10 lanes per edge,
// each lane loads 4 bf16 (dwordx2) -> 4x fewer gather addresses than scalar.
__global__ __launch_bounds__(256) void k_spmm4(const int* __restrict__ ptr,
                                               const int2* __restrict__ ep,
                                               const unsigned short* __restrict__ cur,
                                               unsigned short* __restrict__ nxt,
                                               float* __restrict__ out,
                                               const float* __restrict__ gamma, int k) {
    int wave = (blockIdx.x * blockDim.x + threadIdx.x) >> 6;
    int lane = threadIdx.x & 63;
    if (wave >= NN) return;
    int e0 = ptr[wave], e1 = ptr[wave + 1];
    int es = lane / 10;            // 0..6 (6 => lanes 60-63 inactive)
    int fq = lane - es * 10;       // 0..9
    bool act = es < 6;
    float a0 = 0.f, a1 = 0.f, a2 = 0.f, a3 = 0.f;

    for (int base = e0; base < e1; base += 12) {
        int2 p = make_int2(0, 0);
        int li = base + lane;
        if (lane < 12 && li < e1) p = ep[li];       // coalesced
        int   sA = __shfl(p.x, es);
        float nA = __int_as_float(__shfl(p.y, es));
        int   sB = __shfl(p.x, es + 6);
        float nB = __int_as_float(__shfl(p.y, es + 6));
        if (act && base + es < e1) {
            uint2 u = *((const uint2*)(cur + (size_t)sA * OUT_DIM) + fq);
            a0 += nA * __uint_as_float(u.x << 16);
            a1 += nA * __uint_as_float(u.x & 0xFFFF0000u);
            a2 += nA * __uint_as_float(u.y << 16);
            a3 += nA * __uint_as_float(u.y & 0xFFFF0000u);
        }
        if (act && base + 6 + es < e1) {
            uint2 u = *((const uint2*)(cur + (size_t)sB * OUT_DIM) + fq);
            a0 += nB * __uint_as_float(u.x << 16);
            a1 += nB * __uint_as_float(u.x & 0xFFFF0000u);
            a2 += nB * __uint_as_float(u.y << 16);
            a3 += nB * __uint_as_float(u.y & 0xFFFF0000u);
        }
    }
    // reduce across the 6 edge slots: lanes fq, fq+10, ..., fq+50
    float s0 = a0, s1 = a1, s2 = a2, s3 = a3;
#pragma unroll
    for (int j = 1; j < 6; ++j) {
        s0 += __shfl(a0, fq + j * 10);
        s1 += __shfl(a1, fq + j * 10);
        s2 += __shfl(a2, fq + j * 10);
        s3 += __shfl(a3, fq + j * 10);
    }
    if (lane < 10) {
        uint2 w;
        w.x = (unsigned)bf16_rne(s0) | ((unsigned)bf16_rne(s1) << 16);
        w.y = (unsigned)bf16_rne(s2) | ((unsigned)bf16_rne(s3) << 16);
        *((uint2*)(nxt + (size_t)wave * OUT_DIM) + lane) = w;
        float gk = gamma[k];
        float4* op = (float4*)(out + (size_t)wave * OUT_DIM) + lane;
        float4 ov = *op;
        ov.x += gk * s0; ov.y += gk * s1; ov.z += gk * s2; ov.w += gk * s3;
        *op = ov;
    }
}

extern "C" void kernel_launch(void* const* d_in, const int* in_sizes, int n_in,
                              void* d_out, int out_size, void* d_ws, size_t ws_size,
                              hipStream_t stream) {
    const float* x   = (const float*)d_in[0];
    const int*   ei  = (const int*)d_in[1];
    const float* W1  = (const float*)d_in[2];
    const float* b1  = (const float*)d_in[3];
    const float* bnw = (const float*)d_in[4];
    const float* bnb = (const float*)d_in[5];
    const float* bnm = (const float*)d_in[6];
    const float* bnv = (const float*)d_in[7];
    const float* W2  = (const float*)d_in[8];
    const float* b2  = (const float*)d_in[9];
    const float* gamma = (const float*)d_in[10];
    float* out = (float*)d_out;

    char* ws = (char*)d_ws;
    const size_t A = 256;
    auto pad = [&](size_t b) { return (b + A - 1) / A * A; };
    size_t off = 0;
    int*   bptr   = (int*)  (ws + off); off += pad((size_t)(NB + 1) * 4);
    int*   totB   = (int*)  (ws + off); off += pad((size_t)NB * 4);
    float* dinv   = (float*)(ws + off); off += pad((size_t)NN * 4);
    int*   ptr    = (int*)  (ws + off); off += pad((size_t)(NN + 1) * 4);
    int2*  epackB = (int2*) (ws + off); off += pad((size_t)EE * 8);
    float* h      = (float*)(ws + off); off += pad((size_t)NN * HID * 4);
    unsigned short* ping = (unsigned short*)(ws + off); off += pad((size_t)NN * OUT_DIM * 2);
    unsigned short* pong = (unsigned short*)(ws + off); off += pad((size_t)NN * OUT_DIM * 2);
    unsigned short* w1h = (unsigned short*)(ws + off); off += pad((size_t)HID * IN_DIM * 2);
    unsigned short* w1l = (unsigned short*)(ws + off); off += pad((size_t)HID * IN_DIM * 2);

    // histR8/histB alias h (h written later by gemm1m, after scatterB/sortB consumed them)
    unsigned* histR8 = (unsigned*)h;                              // HB*HRW*4 = 12.8 MB
    int* histB = (int*)((char*)h + (size_t)HB * HRW * 4);         // HB*NB*4 = 1.31 MB

    // graph build: LDS histograms -> 2D prefix -> bucketed scatter -> in-bucket CSC sort
    k_hist<<<HB, 256, 0, stream>>>(ei, histR8, histB);
    k_dinv2<<<(NN + 255) / 256, 256, 0, stream>>>(histR8, dinv);
    k_colsumB<<<(NB + 255) / 256, 256, 0, stream>>>(histB, totB);
    k_scanT<<<1, 256, 0, stream>>>(totB, bptr);
    k_scatterB<<<HB, 256, 0, stream>>>(ei, dinv, bptr, histB, epackB);
    k_sortB<<<NB, 256, 0, stream>>>(bptr, epackB, ptr);

    // MLP
    k_w1split<<<(HID * IN_DIM + 255) / 256, 256, 0, stream>>>(W1, w1h, w1l);
    k_gemm1m<<<(NN + BM - 1) / BM, 256, 0, stream>>>(x, w1h, w1l, b1, bnw, bnb, bnm, bnv, h);
    k_gemm2<<<(NN + 255) / 256, 256, 0, stream>>>(h, W2, b2, gamma, ping, out);

    // K propagation steps, ping-pong (bf16 state, fp32 out accumulation)
    unsigned short* cur = ping;
    unsigned short* nxt = pong;
    for (int k = 1; k <= KSTEPS; ++k) {
        k_spmm4<<<(NN * 64 + 255) / 256, 256, 0, stream>>>(ptr, epackB, cur, nxt, out, gamma, k);
        unsigned short* t = cur; cur = nxt; nxt = t;
    }
}

// Round 10
// 515.643 us; speedup vs baseline: 7.1209x; 1.0382x over previous
//
#include <hip/hip_runtime.h>
#include <cstddef>

#define NN 50000
#define EE 1600000
#define IN_DIM 512
#define HID 256
#define OUT_DIM 40
#define KSTEPS 10
#define BN_EPS 1e-5f

#define HB 256                 // histogram/scatter blocks
#define ECHUNK (EE / HB)       // 6250 edges per block
#define BNODE 40               // dest nodes per bucket
#define NB 1280                // buckets (covers 51200 >= NN)
#define HRW ((NN + 3) / 4)     // 12500 words of packed byte counts
#define SORTCAP 3072           // max edges per bucket (mean 1250)

typedef __attribute__((ext_vector_type(8))) short short8;
typedef __attribute__((ext_vector_type(4))) float f32x4;

__device__ inline unsigned short bf16_rne(float v) {
    union { float f; unsigned u; } c; c.f = v;
    unsigned u = c.u;
    unsigned r = u + 0x7fff + ((u >> 16) & 1);
    return (unsigned short)(r >> 16);
}
__device__ inline float bf16_to_f(unsigned short h) {
    union { unsigned u; float f; } c; c.u = ((unsigned)h) << 16;
    return c.f;
}

// ---------------- phase 1: LDS histograms (row-degree bytes + col buckets) ----------------
__global__ __launch_bounds__(256) void k_hist(const int* __restrict__ ei,
                                              unsigned* __restrict__ histR8,
                                              int* __restrict__ histB) {
    __shared__ unsigned hr[HRW];   // 50 KB
    __shared__ int hb[NB];         // 5 KB
    int b = blockIdx.x, tid = threadIdx.x;
    for (int i = tid; i < HRW; i += 256) hr[i] = 0;
    for (int i = tid; i < NB; i += 256) hb[i] = 0;
    __syncthreads();
    int e0 = b * ECHUNK;
    for (int e = e0 + tid; e < e0 + ECHUNK; e += 256) {
        int r = ei[e];
        int c = ei[EE + e];
        atomicAdd(&hr[r >> 2], 1u << ((r & 3) * 8));
        atomicAdd(&hb[(unsigned)c / BNODE], 1);
    }
    __syncthreads();
    unsigned* o = histR8 + (size_t)b * HRW;
    for (int i = tid; i < HRW; i += 256) o[i] = hr[i];
    int* ob = histB + (size_t)b * NB;
    for (int i = tid; i < NB; i += 256) ob[i] = hb[i];
}

// ---------------- row-degree reduce -> dinv ----------------
__global__ void k_dinv2(const unsigned* __restrict__ histR8, float* __restrict__ dinv) {
    int i = blockIdx.x * blockDim.x + threadIdx.x;
    if (i >= NN) return;
    int word = i >> 2, sh = (i & 3) * 8;
    int d = 0;
    for (int blk = 0; blk < HB; ++blk)
        d += (histR8[(size_t)blk * HRW + word] >> sh) & 0xFFu;
    float fd = d < 1 ? 1.0f : (float)d;
    dinv[i] = 1.0f / sqrtf(fd);
}

// ---------------- per-bucket prefix across blocks ----------------
__global__ void k_colsumB(int* __restrict__ histB, int* __restrict__ totB) {
    int t = blockIdx.x * blockDim.x + threadIdx.x;
    if (t >= NB) return;
    int run = 0;
    for (int blk = 0; blk < HB; ++blk) {
        size_t idx = (size_t)blk * NB + t;
        int v = histB[idx];
        histB[idx] = run;
        run += v;
    }
    totB[t] = run;
}

// ---------------- exclusive scan of 1280 bucket totals -> bptr ----------------
__global__ __launch_bounds__(256) void k_scanT(const int* __restrict__ totB,
                                               int* __restrict__ bptr) {
    __shared__ int wsum[4];
    int tid = threadIdx.x;
    int loc[5], s = 0;
#pragma unroll
    for (int j = 0; j < 5; ++j) { loc[j] = totB[tid * 5 + j]; s += loc[j]; }
    int lane = tid & 63, w = tid >> 6, v = s;
    for (int d = 1; d < 64; d <<= 1) {
        int t = __shfl_up(v, d);
        if (lane >= d) v += t;
    }
    if (lane == 63) wsum[w] = v;
    __syncthreads();
    if (w == 0 && lane < 4) {
        int t = wsum[lane];
        for (int d = 1; d < 4; d <<= 1) {
            int u = __shfl_up(t, d);
            if (lane >= d) t += u;
        }
        wsum[lane] = t;
    }
    __syncthreads();
    int run = (w > 0 ? wsum[w - 1] : 0) + (v - s);
#pragma unroll
    for (int j = 0; j < 5; ++j) { bptr[tid * 5 + j] = run; run += loc[j]; }
    if (tid == 255) bptr[NB] = run;   // == EE
}

// ---------------- phase 2: scatter into buckets via LDS cursors ----------------
__global__ __launch_bounds__(256) void k_scatterB(const int* __restrict__ ei,
                                                  const float* __restrict__ dinv,
                                                  const int* __restrict__ bptr,
                                                  const int* __restrict__ histB,
                                                  int2* __restrict__ ep) {
    __shared__ int cur[NB];
    int b = blockIdx.x, tid = threadIdx.x;
    for (int i = tid; i < NB; i += 256) cur[i] = bptr[i] + histB[(size_t)b * NB + i];
    __syncthreads();
    int e0 = b * ECHUNK;
    for (int e = e0 + tid; e < e0 + ECHUNK; e += 256) {
        int r = ei[e];
        int c = ei[EE + e];
        int bk = (unsigned)c / BNODE;
        int pos = atomicAdd(&cur[bk], 1);
        int2 p;
        p.x = r | ((c - bk * BNODE) << 16);   // src:16b | col_local:6b
        p.y = __float_as_int(dinv[r] * dinv[c]);
        ep[pos] = p;
    }
}

// ---------------- phase 3: in-bucket sort to exact CSC + node ptr emit ----------------
__global__ __launch_bounds__(256) void k_sortB(const int* __restrict__ bptr,
                                               int2* __restrict__ ep,
                                               int* __restrict__ ptr) {
    __shared__ int2 buf[SORTCAP];   // 24 KB
    __shared__ int h40[BNODE];
    __shared__ int pfx[BNODE + 1];
    int b = blockIdx.x, tid = threadIdx.x;
    int e0 = bptr[b], e1 = bptr[b + 1], n = e1 - e0;
    if (tid < BNODE) h40[tid] = 0;
    __syncthreads();
    for (int i = tid; i < n; i += 256) {
        int2 p = ep[e0 + i];
        buf[i] = p;
        atomicAdd(&h40[p.x >> 16], 1);
    }
    __syncthreads();
    if (tid == 0) {
        int run = 0;
#pragma unroll
        for (int j = 0; j < BNODE; ++j) { pfx[j] = run; run += h40[j]; }
        pfx[BNODE] = run;
    }
    __syncthreads();
    if (tid < BNODE) {
        int node = b * BNODE + tid;
        if (node < NN) ptr[node] = e0 + pfx[tid];
        h40[tid] = pfx[tid];     // becomes cursor
    }
    if (tid == 64 && b * BNODE + BNODE >= NN) ptr[NN] = e1;
    __syncthreads();
    for (int i = tid; i < n; i += 256) {
        int2 p = buf[i];
        int cl = p.x >> 16;
        int pos = atomicAdd(&h40[cl], 1);
        int2 q;
        q.x = p.x & 0xFFFF;      // plain src index
        q.y = p.y;
        ep[e0 + pos] = q;
    }
}

// ---------------- W1 -> bf16 hi/lo split ----------------
__global__ void k_w1split(const float* __restrict__ W1, unsigned short* __restrict__ w1h,
                          unsigned short* __restrict__ w1l) {
    int i = blockIdx.x * blockDim.x + threadIdx.x;
    if (i >= HID * IN_DIM) return;
    float v = W1[i];
    unsigned short h = bf16_rne(v);
    unsigned short l = bf16_rne(v - bf16_to_f(h));
    w1h[i] = h;
    w1l[i] = l;
}

// ---------------- GEMM1 via split-bf16 MFMA: h = relu(BN(x @ W1^T + b1)) ----------------
// BM=64, BN split in halves of 128 (grid 782x2), BK=32. 4 waves, wave tile 64x32
// (acc 4x2). 24 KB LDS -> 6 blocks/CU; no reg-prefetch (TLP hides load latency).
#define BM 64
#define BK 32
__device__ inline int swzA(int row, int b) {
    return row * 64 + (b ^ (int)((((unsigned)row >> 1) & 3u) << 4));
}
__global__ __launch_bounds__(256, 6) void k_gemm1m(const float* __restrict__ x,
                                                   const unsigned short* __restrict__ w1h,
                                                   const unsigned short* __restrict__ w1l,
                                                   const float* __restrict__ b1,
                                                   const float* __restrict__ bnw,
                                                   const float* __restrict__ bnb,
                                                   const float* __restrict__ bnm,
                                                   const float* __restrict__ bnv,
                                                   float* __restrict__ h) {
    __shared__ __align__(16) unsigned short Ah[BM * BK];    // 4 KB
    __shared__ __align__(16) unsigned short Al[BM * BK];    // 4 KB
    __shared__ __align__(16) unsigned short Bh[128 * BK];   // 8 KB
    __shared__ __align__(16) unsigned short Bl[128 * BK];   // 8 KB
    int tid = threadIdx.x;
    int lane = tid & 63;
    int wn = tid >> 6;            // 0..3 -> 32-col slice
    int brow = blockIdx.x * BM;
    int bcol = blockIdx.y * 128;

    // A staging: 4 threads/row, 16B chunk each
    int ra = tid >> 2, ck = tid & 3;
    // B staging: 2 threads/row (128 rows), 16 bf16 each
    int rb = tid >> 1, cbs = (tid & 1) * 16;

    bool rok = (brow + ra) < NN;
    const float* xa = x + (size_t)(brow + ra) * IN_DIM + ck * 8;
    const unsigned short* bhp = w1h + (size_t)(bcol + rb) * IN_DIM + cbs;
    const unsigned short* blp = w1l + (size_t)(bcol + rb) * IN_DIM + cbs;

    f32x4 acc[4][2];
#pragma unroll
    for (int i = 0; i < 4; ++i)
#pragma unroll
        for (int j = 0; j < 2; ++j) acc[i][j] = (f32x4){0.f, 0.f, 0.f, 0.f};

    int frA = lane & 15;               // + mi*16 -> A row
    int frB = wn * 32 + (lane & 15);   // + ni*16 -> B row (0..127)
    int fko = (lane >> 4) * 16;        // byte offset of lane's 8-bf16 K-slice

    for (int kt = 0; kt < IN_DIM; kt += BK) {
        // loads for this tile (latency covered by other resident blocks)
        float4 v0 = make_float4(0.f, 0.f, 0.f, 0.f), v1 = v0;
        if (rok) { v0 = *(const float4*)(xa + kt); v1 = *(const float4*)(xa + kt + 4); }
        short8 gh0 = *(const short8*)(bhp + kt);
        short8 gh1 = *(const short8*)(bhp + kt + 8);
        short8 gl0 = *(const short8*)(blp + kt);
        short8 gl1 = *(const short8*)(blp + kt + 8);
        union { unsigned short u[8]; short8 v; } uh, ul;
        {
            float vv[8] = {v0.x, v0.y, v0.z, v0.w, v1.x, v1.y, v1.z, v1.w};
#pragma unroll
            for (int j = 0; j < 8; ++j) {
                unsigned short hh = bf16_rne(vv[j]);
                uh.u[j] = hh;
                ul.u[j] = bf16_rne(vv[j] - bf16_to_f(hh));
            }
        }
        __syncthreads();   // previous tile's readers done
        {
            int ab = swzA(ra, ck * 16);
            *(short8*)((char*)Ah + ab) = uh.v;
            *(short8*)((char*)Al + ab) = ul.v;
            int bb0 = swzA(rb, cbs * 2);
            int bb1 = swzA(rb, cbs * 2 + 16);
            *(short8*)((char*)Bh + bb0) = gh0;
            *(short8*)((char*)Bh + bb1) = gh1;
            *(short8*)((char*)Bl + bb0) = gl0;
            *(short8*)((char*)Bl + bb1) = gl1;
        }
        __syncthreads();   // tile ready

        short8 afh[4], afl[4];
#pragma unroll
        for (int mi = 0; mi < 4; ++mi) {
            int byte = swzA(frA + mi * 16, fko);
            afh[mi] = *(short8*)((char*)Ah + byte);
            afl[mi] = *(short8*)((char*)Al + byte);
        }
#pragma unroll
        for (int ni = 0; ni < 2; ++ni) {
            int byte = swzA(frB + ni * 16, fko);
            short8 bh = *(short8*)((char*)Bh + byte);
            short8 bl = *(short8*)((char*)Bl + byte);
#pragma unroll
            for (int mi = 0; mi < 4; ++mi) {
                acc[mi][ni] = __builtin_amdgcn_mfma_f32_16x16x32_bf16(afh[mi], bh, acc[mi][ni], 0, 0, 0);
                acc[mi][ni] = __builtin_amdgcn_mfma_f32_16x16x32_bf16(afl[mi], bh, acc[mi][ni], 0, 0, 0);
                acc[mi][ni] = __builtin_amdgcn_mfma_f32_16x16x32_bf16(afh[mi], bl, acc[mi][ni], 0, 0, 0);
            }
        }
    }

    // epilogue: BN + ReLU; C/D layout col=lane&15, row=(lane>>4)*4+j
    int cbase = bcol + wn * 32 + (lane & 15);
    float scl[2], off[2];
#pragma unroll
    for (int ni = 0; ni < 2; ++ni) {
        int c = cbase + ni * 16;
        float s = bnw[c] * rsqrtf(bnv[c] + BN_EPS);
        scl[ni] = s;
        off[ni] = (b1[c] - bnm[c]) * s + bnb[c];
    }
#pragma unroll
    for (int mi = 0; mi < 4; ++mi) {
        int r0 = brow + mi * 16 + ((lane >> 4) << 2);
#pragma unroll
        for (int ni = 0; ni < 2; ++ni) {
            int c = cbase + ni * 16;
#pragma unroll
            for (int j = 0; j < 4; ++j) {
                int r = r0 + j;
                if (r < NN) {
                    float v = acc[mi][ni][j] * scl[ni] + off[ni];
                    h[(size_t)r * HID + c] = v > 0.f ? v : 0.f;
                }
            }
        }
    }
}

// ---------------- GEMM2: z = h @ W2^T + b2; ping = bf16(z); out = gamma0 * z ----------------
__global__ __launch_bounds__(256) void k_gemm2(const float* __restrict__ h,
                                               const float* __restrict__ W2,
                                               const float* __restrict__ b2,
                                               const float* __restrict__ gamma,
                                               unsigned short* __restrict__ ping,
                                               float* __restrict__ out) {
    __shared__ float W2T[HID * OUT_DIM];
    int tid = threadIdx.x;
    for (int i = tid; i < HID * OUT_DIM; i += 256) {
        int o = i / HID;
        int k = i - o * HID;
        W2T[k * OUT_DIM + o] = W2[i];
    }
    __syncthreads();
    int n = blockIdx.x * 256 + tid;
    if (n >= NN) return;

    float4 acc[10];
#pragma unroll
    for (int o4 = 0; o4 < 10; ++o4) acc[o4] = *(const float4*)&b2[o4 * 4];

    const float4* hr = (const float4*)(h + (size_t)n * HID);
    const float4* wt = (const float4*)W2T;
    for (int j = 0; j < HID / 4; ++j) {
        float4 hv = hr[j];
#pragma unroll
        for (int c = 0; c < 4; ++c) {
            float hk = (c == 0) ? hv.x : (c == 1) ? hv.y : (c == 2) ? hv.z : hv.w;
            const float4* wr = wt + (size_t)(j * 4 + c) * 10;
#pragma unroll
            for (int o4 = 0; o4 < 10; ++o4) {
                float4 w = wr[o4];
                acc[o4].x += hk * w.x;
                acc[o4].y += hk * w.y;
                acc[o4].z += hk * w.z;
                acc[o4].w += hk * w.w;
            }
        }
    }
    float g0 = gamma[0];
    uint2* pp = (uint2*)(ping + (size_t)n * OUT_DIM);
    float4* op = (float4*)(out + (size_t)n * OUT_DIM);
#pragma unroll
    for (int o4 = 0; o4 < 10; ++o4) {
        uint2 w;
        w.x = (unsigned)bf16_rne(acc[o4].x) | ((unsigned)bf16_rne(acc[o4].y) << 16);
        w.y = (unsigned)bf16_rne(acc[o4].z) | ((unsigned)bf16_rne(acc[o4].w) << 16);
        pp[o4] = w;
        float4 g;
        g.x = g0 * acc[o4].x; g.y = g0 * acc[o4].y;
        g.z = g0 * acc[o4].z; g.w = g0 * acc[o4].w;
        op[o4] = g;
    }
}

// ---------------- propagation step: wave-per-node, 48 edges/round, no shfl broadcast ----------------
// lane -> (edge_slot es=lane/10, feature_quad fq=lane%10). Each lane loads its
// group's edge directly (HW merges the 10 same-address lanes); out-of-range
// slots load {0,0} so nm=0 and the unconditional row-0 gather contributes 0.
// 8 independent gather chains per round; most nodes finish in one round.
__global__ __launch_bounds__(256) void k_spmm5(const int* __restrict__ ptr,
                                               const int2* __restrict__ ep,
                                               const unsigned short* __restrict__ cur,
                                               unsigned short* __restrict__ nxt,
                                               float* __restrict__ out,
                                               const float* __restrict__ gamma, int k) {
    int wave = (blockIdx.x * blockDim.x + threadIdx.x) >> 6;
    int lane = threadIdx.x & 63;
    if (wave >= NN) return;
    int e0 = ptr[wave], e1 = ptr[wave + 1];
    int es = lane / 10;            // 0..6 (6 => lanes 60-63 idle)
    int fq = lane - es * 10;       // 0..9
    bool act = es < 6;
    float a0 = 0.f, a1 = 0.f, a2 = 0.f, a3 = 0.f;

    for (int base = e0; base < e1; base += 48) {
        int2 pp[8];
#pragma unroll
        for (int g = 0; g < 8; ++g) {
            int e = base + g * 6 + es;
            pp[g] = (act && e < e1) ? ep[e] : make_int2(0, 0);
        }
#pragma unroll
        for (int g = 0; g < 8; ++g) {
            uint2 u = *((const uint2*)(cur + (size_t)pp[g].x * OUT_DIM) + fq);
            float nm = __int_as_float(pp[g].y);
            a0 += nm * __uint_as_float(u.x << 16);
            a1 += nm * __uint_as_float(u.x & 0xFFFF0000u);
            a2 += nm * __uint_as_float(u.y << 16);
            a3 += nm * __uint_as_float(u.y & 0xFFFF0000u);
        }
    }
    // reduce across the 6 edge slots: lanes fq, fq+10, ..., fq+50
    float s0 = a0, s1 = a1, s2 = a2, s3 = a3;
#pragma unroll
    for (int j = 1; j < 6; ++j) {
        s0 += __shfl(a0, fq + j * 10);
        s1 += __shfl(a1, fq + j * 10);
        s2 += __shfl(a2, fq + j * 10);
        s3 += __shfl(a3, fq + j * 10);
    }
    if (lane < 10) {
        uint2 w;
        w.x = (unsigned)bf16_rne(s0) | ((unsigned)bf16_rne(s1) << 16);
        w.y = (unsigned)bf16_rne(s2) | ((unsigned)bf16_rne(s3) << 16);
        *((uint2*)(nxt + (size_t)wave * OUT_DIM) + lane) = w;
        float gk = gamma[k];
        float4* op = (float4*)(out + (size_t)wave * OUT_DIM) + lane;
        float4 ov = *op;
        ov.x += gk * s0; ov.y += gk * s1; ov.z += gk * s2; ov.w += gk * s3;
        *op = ov;
    }
}

extern "C" void kernel_launch(void* const* d_in, const int* in_sizes, int n_in,
                              void* d_out, int out_size, void* d_ws, size_t ws_size,
                              hipStream_t stream) {
    const float* x   = (const float*)d_in[0];
    const int*   ei  = (const int*)d_in[1];
    const float* W1  = (const float*)d_in[2];
    const float* b1  = (const float*)d_in[3];
    const float* bnw = (const float*)d_in[4];
    const float* bnb = (const float*)d_in[5];
    const float* bnm = (const float*)d_in[6];
    const float* bnv = (const float*)d_in[7];
    const float* W2  = (const float*)d_in[8];
    const float* b2  = (const float*)d_in[9];
    const float* gamma = (const float*)d_in[10];
    float* out = (float*)d_out;

    char* ws = (char*)d_ws;
    const size_t A = 256;
    auto pad = [&](size_t b) { return (b + A - 1) / A * A; };
    size_t off = 0;
    int*   bptr   = (int*)  (ws + off); off += pad((size_t)(NB + 1) * 4);
    int*   totB   = (int*)  (ws + off); off += pad((size_t)NB * 4);
    float* dinv   = (float*)(ws + off); off += pad((size_t)NN * 4);
    int*   ptr    = (int*)  (ws + off); off += pad((size_t)(NN + 1) * 4);
    int2*  epackB = (int2*) (ws + off); off += pad((size_t)EE * 8);
    float* h      = (float*)(ws + off); off += pad((size_t)NN * HID * 4);
    unsigned short* ping = (unsigned short*)(ws + off); off += pad((size_t)NN * OUT_DIM * 2);
    unsigned short* pong = (unsigned short*)(ws + off); off += pad((size_t)NN * OUT_DIM * 2);
    unsigned short* w1h = (unsigned short*)(ws + off); off += pad((size_t)HID * IN_DIM * 2);
    unsigned short* w1l = (unsigned short*)(ws + off); off += pad((size_t)HID * IN_DIM * 2);

    // histR8/histB alias h (h written later by gemm1m, after scatterB/sortB consumed them)
    unsigned* histR8 = (unsigned*)h;                              // HB*HRW*4 = 12.8 MB
    int* histB = (int*)((char*)h + (size_t)HB * HRW * 4);         // HB*NB*4 = 1.31 MB

    // graph build: LDS histograms -> 2D prefix -> bucketed scatter -> in-bucket CSC sort
    k_hist<<<HB, 256, 0, stream>>>(ei, histR8, histB);
    k_dinv2<<<(NN + 255) / 256, 256, 0, stream>>>(histR8, dinv);
    k_colsumB<<<(NB + 255) / 256, 256, 0, stream>>>(histB, totB);
    k_scanT<<<1, 256, 0, stream>>>(totB, bptr);
    k_scatterB<<<HB, 256, 0, stream>>>(ei, dinv, bptr, histB, epackB);
    k_sortB<<<NB, 256, 0, stream>>>(bptr, epackB, ptr);

    // MLP
    k_w1split<<<(HID * IN_DIM + 255) / 256, 256, 0, stream>>>(W1, w1h, w1l);
    dim3 g1((NN + BM - 1) / BM, 2);
    k_gemm1m<<<g1, 256, 0, stream>>>(x, w1h, w1l, b1, bnw, bnb, bnm, bnv, h);
    k_gemm2<<<(NN + 255) / 256, 256, 0, stream>>>(h, W2, b2, gamma, ping, out);

    // K propagation steps, ping-pong (bf16 state, fp32 out accumulation)
    unsigned short* cur = ping;
    unsigned short* nxt = pong;
    for (int k = 1; k <= KSTEPS; ++k) {
        k_spmm5<<<(NN * 64 + 255) / 256, 256, 0, stream>>>(ptr, epackB, cur, nxt, out, gamma, k);
        unsigned short* t = cur; cur = nxt; nxt = t;
    }
}